// Round 8
// baseline (1521.543 us; speedup 1.0000x reference)
//
#include <hip/hip_runtime.h>
#include <hip/hip_bf16.h>

#define CDIV(a, b) (((a) + (b) - 1) / (b))

typedef __attribute__((ext_vector_type(8))) __bf16 bf16x8;
typedef __attribute__((ext_vector_type(4))) float f32x4;

__device__ __forceinline__ float bf2f(unsigned short u) {
  union { unsigned int i; float f; } c; c.i = ((unsigned int)u) << 16; return c.f;
}
__device__ __forceinline__ unsigned short f2bf(float f) {
  union { float f; unsigned int i; } c; c.f = f;
  unsigned int r = c.i + 0x7fffu + ((c.i >> 16) & 1u);
  return (unsigned short)(r >> 16);
}
// packed hi/lo (u32 = hi | lo<<16) helpers
__device__ __forceinline__ float dec1(unsigned int u) {
  union { unsigned int i; float f; } a, b;
  a.i = u << 16; b.i = u & 0xffff0000u;
  return a.f + b.f;
}
__device__ __forceinline__ unsigned int packhl(float v) {
  unsigned short h = f2bf(v);
  unsigned short l = f2bf(v - bf2f(h));
  return (unsigned int)h | ((unsigned int)l << 16);
}

// ---- dtype detector: flag=1 if buffers are fp32 storage, 0 if bf16 storage ----
__global__ void k_detect(const unsigned short* __restrict__ xq, int nsamp, int* __restrict__ flagp) {
  __shared__ float sm[256];
  int t = threadIdx.x;
  float mx = 0.f;
  for (int i = t; i < nsamp; i += 256) {
    float v = bf2f(xq[i]);
    if (!(v == v)) v = 1e30f;
    mx = fmaxf(mx, fabsf(v));
  }
  sm[t] = mx; __syncthreads();
  for (int o = 128; o > 0; o >>= 1) {
    if (t < o) sm[t] = fmaxf(sm[t], sm[t + o]);
    __syncthreads();
  }
  if (t == 0) *flagp = (sm[0] > 1e6f) ? 1 : 0;
}

// ---- generic convert to fp32 ----
__global__ void k_cvt(const void* __restrict__ src, float* __restrict__ dst, int n,
                      const int* __restrict__ flagp) {
  int i = blockIdx.x * 256 + threadIdx.x;
  if (i >= n) return;
  if (*flagp) dst[i] = ((const float*)src)[i];
  else        dst[i] = bf2f(((const unsigned short*)src)[i]);
}

// ---- weight: W[K,256] -> transposed hi/lo bf16 Bt[256,K] (separate arrays) ----
__global__ void k_wsplit(const void* __restrict__ W, unsigned short* __restrict__ Bth,
                         unsigned short* __restrict__ Btl, int K, const int* __restrict__ flagp) {
  int i = blockIdx.x * 256 + threadIdx.x;
  if (i >= K * 256) return;
  int k = i >> 8, n = i & 255;
  float v = (*flagp) ? ((const float*)W)[i] : bf2f(((const unsigned short*)W)[i]);
  unsigned short h = f2bf(v);
  Bth[(size_t)n * K + k] = h;
  Btl[(size_t)n * K + k] = f2bf(v - bf2f(h));
}

// ---- x -> packed hi/lo u32 (dual dtype) ----
__global__ void k_splitpack(const void* __restrict__ x, unsigned int* __restrict__ Xp, int n,
                            const int* __restrict__ flagp) {
  int i = blockIdx.x * 256 + threadIdx.x;
  if (i >= n) return;
  float v = (*flagp) ? ((const float*)x)[i] : bf2f(((const unsigned short*)x)[i]);
  Xp[i] = packhl(v);
}

__global__ void k_zero_i32(int* p, int n) {
  int i = blockIdx.x * 256 + threadIdx.x;
  if (i < n) p[i] = 0;
}

// ---------------- CSR build ----------------
__global__ void k_deg(const int* __restrict__ dst, int* __restrict__ deg, int E) {
  int e = blockIdx.x * 256 + threadIdx.x;
  if (e < E) atomicAdd(&deg[dst[e]], 1);
}
__global__ void k_scan1(const int* __restrict__ in, int* __restrict__ out, int* __restrict__ bsums, int n) {
  __shared__ int sh[256];
  int t = threadIdx.x, i = blockIdx.x * 256 + t;
  int v = (i < n) ? in[i] : 0;
  sh[t] = v; __syncthreads();
  for (int o = 1; o < 256; o <<= 1) {
    int add = (t >= o) ? sh[t - o] : 0;
    __syncthreads();
    sh[t] += add;
    __syncthreads();
  }
  if (i < n) out[i] = sh[t] - v;
  if (t == 255) bsums[blockIdx.x] = sh[255];
}
__global__ void k_scan2(int* bsums, int nb) {
  __shared__ int sh[256];
  int t = threadIdx.x;
  int v = (t < nb) ? bsums[t] : 0;
  sh[t] = v; __syncthreads();
  for (int o = 1; o < 256; o <<= 1) {
    int add = (t >= o) ? sh[t - o] : 0;
    __syncthreads();
    sh[t] += add;
    __syncthreads();
  }
  if (t < nb) bsums[t] = sh[t] - v;
}
__global__ void k_scan3(int* offs, const int* bsums, int n, int etot) {
  int i = blockIdx.x * 256 + threadIdx.x;
  if (i < n) offs[i] += bsums[blockIdx.x];
  if (i == 0) offs[n] = etot;
}
__global__ void k_copy_i32(const int* __restrict__ a, int* __restrict__ b, int n) {
  int i = blockIdx.x * 256 + threadIdx.x;
  if (i < n) b[i] = a[i];
}
__global__ void k_fill(const int* __restrict__ dst, const int* __restrict__ src,
                       int* __restrict__ cursor, int* __restrict__ csr_src, int E) {
  int e = blockIdx.x * 256 + threadIdx.x;
  if (e >= E) return;
  int pos = atomicAdd(&cursor[dst[e]], 1);
  csr_src[pos] = src[e];
}
// per-node insertion sort -> deterministic neighbor order
__global__ void k_sortcsr(const int* __restrict__ offs, int* __restrict__ csr, int n) {
  int v = blockIdx.x * 256 + threadIdx.x;
  if (v >= n) return;
  int s = offs[v], e = offs[v + 1];
  for (int i = s + 1; i < e; ++i) {
    int key = csr[i];
    int j = i - 1;
    while (j >= s && csr[j] > key) { csr[j + 1] = csr[j]; --j; }
    csr[j + 1] = key;
  }
}

// ---- fused agg epilogue: H[v] = act(Y[v] + mean_{u in N(v)} Z[u] + b) ----
// one wave per node, lane handles 4 cols (uint4 packed). grid = N/4 blocks of 256.
__global__ void k_aggfuse(const unsigned int* __restrict__ Yp, const unsigned int* __restrict__ Zp,
                          const int* __restrict__ offs, const int* __restrict__ csr,
                          const float* __restrict__ bias, int relu,
                          unsigned int* __restrict__ Hp) {
  int w = threadIdx.x >> 6, lane = threadIdx.x & 63;
  int v = blockIdx.x * 4 + w;
  int c4 = lane * 4;
  uint4 yq = *(const uint4*)&Yp[(size_t)v * 256 + c4];
  int s = offs[v], e = offs[v + 1];
  float a0 = 0.f, a1 = 0.f, a2 = 0.f, a3 = 0.f;
  int i = s;
  for (; i + 2 <= e; i += 2) {
    uint4 z0 = *(const uint4*)&Zp[(size_t)csr[i] * 256 + c4];
    uint4 z1 = *(const uint4*)&Zp[(size_t)csr[i + 1] * 256 + c4];
    a0 += dec1(z0.x) + dec1(z1.x);
    a1 += dec1(z0.y) + dec1(z1.y);
    a2 += dec1(z0.z) + dec1(z1.z);
    a3 += dec1(z0.w) + dec1(z1.w);
  }
  if (i < e) {
    uint4 z0 = *(const uint4*)&Zp[(size_t)csr[i] * 256 + c4];
    a0 += dec1(z0.x); a1 += dec1(z0.y); a2 += dec1(z0.z); a3 += dec1(z0.w);
  }
  float inv = 1.f / fmaxf((float)(e - s), 1.f);
  float4 bv = *(const float4*)&bias[c4];
  float r0 = dec1(yq.x) + a0 * inv + bv.x;
  float r1 = dec1(yq.y) + a1 * inv + bv.y;
  float r2 = dec1(yq.z) + a2 * inv + bv.z;
  float r3 = dec1(yq.w) + a3 * inv + bv.w;
  if (relu) {
    r0 = fmaxf(r0, 0.f); r1 = fmaxf(r1, 0.f);
    r2 = fmaxf(r2, 0.f); r3 = fmaxf(r3, 0.f);
  }
  uint4 o;
  o.x = packhl(r0); o.y = packhl(r1); o.z = packhl(r2); o.w = packhl(r3);
  *(uint4*)&Hp[(size_t)v * 256 + c4] = o;
}

// ---- predictor edge features: E[p] = H[s]*H[d]; one wave per pair ----
__global__ void k_egatherw(const unsigned int* __restrict__ Hp,
                           const int* __restrict__ ps, const int* __restrict__ pd,
                           const int* __restrict__ ns, const int* __restrict__ nd,
                           int base, int nPos, unsigned int* __restrict__ Ep) {
  int w = threadIdx.x >> 6, lane = threadIdx.x & 63;
  int p = blockIdx.x * 4 + w;
  int g = base + p;
  int s, d;
  if (g < nPos) { s = ps[g]; d = pd[g]; }
  else          { s = ns[g - nPos]; d = nd[g - nPos]; }
  int c4 = lane * 4;
  uint4 aq = *(const uint4*)&Hp[(size_t)s * 256 + c4];
  uint4 bq = *(const uint4*)&Hp[(size_t)d * 256 + c4];
  uint4 o;
  o.x = packhl(dec1(aq.x) * dec1(bq.x));
  o.y = packhl(dec1(aq.y) * dec1(bq.y));
  o.z = packhl(dec1(aq.z) * dec1(bq.z));
  o.w = packhl(dec1(aq.w) * dec1(bq.w));
  *(uint4*)&Ep[(size_t)p * 256 + c4] = o;
}

// ---- MFMA GEMM, packed-A: out = A@B^T (+bias, opt relu) ----
// A: packed u32 [M,K]. B: separate hi/lo bf16 [256,K]. 3-product hi/lo split.
// nsel=4: dual-B (nt 0,1 -> B1/O1; nt 2,3 -> B2/O2). nsel=2: single B1/O1.
// Of != null: write fp32 to Of instead of packed to O*.
// grid.x = CDIV(M,128)*nsel, block = 256.
__global__ __launch_bounds__(256) void gemm_packed(
    const unsigned int* __restrict__ Ap, int K,
    const unsigned short* __restrict__ B1h, const unsigned short* __restrict__ B1l,
    const unsigned short* __restrict__ B2h, const unsigned short* __restrict__ B2l,
    const float* __restrict__ bias, int M, int relu, int nsel,
    unsigned int* __restrict__ O1, unsigned int* __restrict__ O2,
    float* __restrict__ Of) {
  __shared__ unsigned short sAh[128 * 40], sAl[128 * 40], sBh[128 * 40], sBl[128 * 40];
  int t = threadIdx.x;
  int mt = blockIdx.x / nsel, nt = blockIdx.x % nsel;
  int m0 = mt * 128;
  const unsigned short* Bh = (nt < 2) ? B1h : B2h;
  const unsigned short* Bl = (nt < 2) ? B1l : B2l;
  unsigned int* Op = (nt < 2) ? O1 : O2;
  int n0 = (nt & 1) * 128;
  int wid = t >> 6, lane = t & 63;
  int wr = (wid >> 1) * 64, wc = (wid & 1) * 64;
  int quad = lane >> 4, lrow = lane & 15;

  f32x4 acc[4][4];
  const f32x4 z4 = {0.f, 0.f, 0.f, 0.f};
#pragma unroll
  for (int i = 0; i < 4; ++i)
#pragma unroll
    for (int j = 0; j < 4; ++j) acc[i][j] = z4;

  int sr = t >> 2;          // staging row 0..63 (+64 on rep 1)
  int c8 = (t & 3) * 8;     // staging col 0,8,16,24

  for (int k0 = 0; k0 < K; k0 += 32) {
#pragma unroll
    for (int rep = 0; rep < 2; ++rep) {
      int r = sr + rep * 64;
      int arow = m0 + r; if (arow >= M) arow = M - 1;
      const unsigned int* ap = &Ap[(size_t)arow * K + k0 + c8];
      uint4 q0 = *(const uint4*)ap;
      uint4 q1 = *(const uint4*)(ap + 4);
      size_t boff = (size_t)(n0 + r) * K + k0 + c8;
      uint4 ubh = *(const uint4*)&Bh[boff];
      uint4 ubl = *(const uint4*)&Bl[boff];
      uint4 hh, ll;
      hh.x = (q0.x & 0xffffu) | (q0.y << 16);
      hh.y = (q0.z & 0xffffu) | (q0.w << 16);
      hh.z = (q1.x & 0xffffu) | (q1.y << 16);
      hh.w = (q1.z & 0xffffu) | (q1.w << 16);
      ll.x = (q0.x >> 16) | (q0.y & 0xffff0000u);
      ll.y = (q0.z >> 16) | (q0.w & 0xffff0000u);
      ll.z = (q1.x >> 16) | (q1.y & 0xffff0000u);
      ll.w = (q1.z >> 16) | (q1.w & 0xffff0000u);
      *(uint4*)&sAh[r * 40 + c8] = hh;
      *(uint4*)&sAl[r * 40 + c8] = ll;
      *(uint4*)&sBh[r * 40 + c8] = ubh;
      *(uint4*)&sBl[r * 40 + c8] = ubl;
    }
    __syncthreads();
    bf16x8 ah[4], al[4], bh[4], bl[4];
#pragma unroll
    for (int i = 0; i < 4; ++i) {
      int ar = (wr + i * 16 + lrow) * 40 + quad * 8;
      int br = (wc + i * 16 + lrow) * 40 + quad * 8;
      ah[i] = *(const bf16x8*)&sAh[ar];
      al[i] = *(const bf16x8*)&sAl[ar];
      bh[i] = *(const bf16x8*)&sBh[br];
      bl[i] = *(const bf16x8*)&sBl[br];
    }
#pragma unroll
    for (int i = 0; i < 4; ++i)
#pragma unroll
      for (int j = 0; j < 4; ++j) {
        acc[i][j] = __builtin_amdgcn_mfma_f32_16x16x32_bf16(ah[i], bh[j], acc[i][j], 0, 0, 0);
        acc[i][j] = __builtin_amdgcn_mfma_f32_16x16x32_bf16(al[i], bh[j], acc[i][j], 0, 0, 0);
        acc[i][j] = __builtin_amdgcn_mfma_f32_16x16x32_bf16(ah[i], bl[j], acc[i][j], 0, 0, 0);
      }
    __syncthreads();
  }

  // epilogue: C/D layout col = lane&15, row = (lane>>4)*4 + reg
#pragma unroll
  for (int j = 0; j < 4; ++j) {
    int gc = n0 + wc + j * 16 + lrow;        // [0,256) within this output matrix
    float bv = bias ? bias[gc] : 0.f;
#pragma unroll
    for (int i = 0; i < 4; ++i) {
#pragma unroll
      for (int rr = 0; rr < 4; ++rr) {
        int gr = m0 + wr + i * 16 + quad * 4 + rr;
        if (gr < M) {
          float v = acc[i][j][rr] + bv;
          if (relu) v = fmaxf(v, 0.f);
          size_t idx = (size_t)gr * 256 + gc;
          if (Of) Of[idx] = v;
          else    Op[idx] = packhl(v);
        }
      }
    }
  }
}

// ---- final 256->1 dot ----
__global__ void k_finaldot(const float* __restrict__ Z2, const float* __restrict__ wp3,
                           const float* __restrict__ bp3, void* __restrict__ out,
                           int base, int Pc, const int* __restrict__ flagp) {
  int wid = threadIdx.x >> 6, lane = threadIdx.x & 63;
  int p = blockIdx.x * 4 + wid;
  if (p >= Pc) return;
  float4 zv = *(const float4*)&Z2[(size_t)p * 256 + lane * 4];
  float s = zv.x * wp3[lane * 4 + 0] + zv.y * wp3[lane * 4 + 1] +
            zv.z * wp3[lane * 4 + 2] + zv.w * wp3[lane * 4 + 3];
#pragma unroll
  for (int o = 32; o >= 1; o >>= 1) s += __shfl_xor(s, o, 64);
  if (lane == 0) {
    float r = s + bp3[0];
    if (*flagp) ((float*)out)[base + p] = r;
    else        ((unsigned short*)out)[base + p] = f2bf(r);
  }
}

extern "C" void kernel_launch(void* const* d_in, const int* in_sizes, int n_in,
                              void* d_out, int out_size, void* d_ws, size_t ws_size,
                              hipStream_t stream) {
  const int N = 50000, E = 800000, P = 100000, DIN = 128, DH = 256;
  const void* x = d_in[0];
  const int* esrc = (const int*)d_in[1];
  const int* edst = (const int*)d_in[2];
  const int* psrc = (const int*)d_in[3];
  const int* pdst = (const int*)d_in[4];
  const int* nsrc = (const int*)d_in[5];
  const int* ndst = (const int*)d_in[6];
  const void* Ws0 = d_in[7];  const void* Wn0 = d_in[8];  const void* b0 = d_in[9];
  const void* Ws1 = d_in[10]; const void* Wn1 = d_in[11]; const void* b1 = d_in[12];
  const void* Ws2 = d_in[13]; const void* Wn2 = d_in[14]; const void* b2 = d_in[15];
  const void* Wp1 = d_in[16]; const void* bp1 = d_in[17];
  const void* Wp2 = d_in[18]; const void* bp2 = d_in[19];
  const void* Wp3 = d_in[20]; const void* bp3 = d_in[21];
  (void)in_sizes; (void)n_in; (void)out_size; (void)ws_size;

  // ---- workspace layout: three packed regions H, Y, Z (u32 [N,256] each) ----
  const size_t NH = (size_t)N * DH;               // 12,800,000
  unsigned int* R_H = (unsigned int*)d_ws;        // H / Xp(L0) / S3
  unsigned int* R_Y = R_H + NH;                   // Y / E / Z2(fp32)
  unsigned int* R_Z = R_Y + NH;                   // Z / Z1
  unsigned short* W16 = (unsigned short*)(R_Z + NH);
  unsigned short* ws0h = W16;                     // K=128 mats: 32768 each
  unsigned short* ws0l = ws0h + 32768;
  unsigned short* wn0h = ws0l + 32768;
  unsigned short* wn0l = wn0h + 32768;
  unsigned short* ws1h = wn0l + 32768;            // K=256 mats: 65536 each
  unsigned short* ws1l = ws1h + 65536;
  unsigned short* wn1h = ws1l + 65536;
  unsigned short* wn1l = wn1h + 65536;
  unsigned short* ws2h = wn1l + 65536;
  unsigned short* ws2l = ws2h + 65536;
  unsigned short* wn2h = ws2l + 65536;
  unsigned short* wn2l = wn2h + 65536;
  unsigned short* wp1h = wn2l + 65536;
  unsigned short* wp1l = wp1h + 65536;
  unsigned short* wp2h = wp1l + 65536;
  unsigned short* wp2l = wp2h + 65536;
  float* FB = (float*)(wp2l + 65536);
  float* b0f  = FB;
  float* b1f  = b0f + 256;
  float* b2f  = b1f + 256;
  float* bp1f = b2f + 256;
  float* bp2f = bp1f + 256;
  float* wp3f = bp2f + 256;
  float* bp3f = wp3f + 256;
  int* deg   = (int*)(bp3f + 4);
  int* offs  = deg + N;
  int* cur   = offs + (N + 1);
  int* bsums = cur + N;
  int* csr   = bsums + 256;
  int* flagp = csr + E;
  // total ~159.3 MB

  unsigned int* Xp = R_H;                 // [N,128] packed (layer-0 A)
  float* Z2f = (float*)R_Y;               // predictor Z2 fp32

  // ---- dtype detection ----
  k_detect<<<1, 256, 0, stream>>>((const unsigned short*)x, 65536, flagp);

  // ---- weight split+transpose, bias cvt ----
  k_wsplit<<<CDIV(DIN * DH, 256), 256, 0, stream>>>(Ws0, ws0h, ws0l, DIN, flagp);
  k_wsplit<<<CDIV(DIN * DH, 256), 256, 0, stream>>>(Wn0, wn0h, wn0l, DIN, flagp);
  k_wsplit<<<CDIV(DH * DH, 256), 256, 0, stream>>>(Ws1, ws1h, ws1l, DH, flagp);
  k_wsplit<<<CDIV(DH * DH, 256), 256, 0, stream>>>(Wn1, wn1h, wn1l, DH, flagp);
  k_wsplit<<<CDIV(DH * DH, 256), 256, 0, stream>>>(Ws2, ws2h, ws2l, DH, flagp);
  k_wsplit<<<CDIV(DH * DH, 256), 256, 0, stream>>>(Wn2, wn2h, wn2l, DH, flagp);
  k_wsplit<<<CDIV(DH * DH, 256), 256, 0, stream>>>(Wp1, wp1h, wp1l, DH, flagp);
  k_wsplit<<<CDIV(DH * DH, 256), 256, 0, stream>>>(Wp2, wp2h, wp2l, DH, flagp);
  k_cvt<<<1, 256, 0, stream>>>(b0,  b0f,  DH, flagp);
  k_cvt<<<1, 256, 0, stream>>>(b1,  b1f,  DH, flagp);
  k_cvt<<<1, 256, 0, stream>>>(b2,  b2f,  DH, flagp);
  k_cvt<<<1, 256, 0, stream>>>(bp1, bp1f, DH, flagp);
  k_cvt<<<1, 256, 0, stream>>>(bp2, bp2f, DH, flagp);
  k_cvt<<<1, 256, 0, stream>>>(Wp3, wp3f, DH, flagp);
  k_cvt<<<1, 256, 0, stream>>>(bp3, bp3f, 1, flagp);

  // ---- CSR build (deterministic: sorted adjacency) ----
  int nb = CDIV(N, 256);
  k_zero_i32<<<nb, 256, 0, stream>>>(deg, N);
  k_deg<<<CDIV(E, 256), 256, 0, stream>>>(edst, deg, E);
  k_scan1<<<nb, 256, 0, stream>>>(deg, offs, bsums, N);
  k_scan2<<<1, 256, 0, stream>>>(bsums, nb);
  k_scan3<<<nb, 256, 0, stream>>>(offs, bsums, N, E);
  k_copy_i32<<<nb, 256, 0, stream>>>(offs, cur, N);
  k_fill<<<CDIV(E, 256), 256, 0, stream>>>(edst, esrc, cur, csr, E);
  k_sortcsr<<<nb, 256, 0, stream>>>(offs, csr, N);

  const int MT = CDIV(N, 128);          // 391

  // ---- Layer 0: Y=x@Ws0, Z=x@Wn0 (dual); H = relu(Y + agg(Z) + b0) ----
  k_splitpack<<<CDIV(N * DIN, 256), 256, 0, stream>>>(x, Xp, N * DIN, flagp);
  gemm_packed<<<MT * 4, 256, 0, stream>>>(Xp, DIN, ws0h, ws0l, wn0h, wn0l,
                                          (float*)0, N, 0, 4, R_Y, R_Z, (float*)0);
  k_aggfuse<<<N / 4, 256, 0, stream>>>(R_Y, R_Z, offs, csr, b0f, 1, R_H);

  // ---- Layer 1 ----
  gemm_packed<<<MT * 4, 256, 0, stream>>>(R_H, DH, ws1h, ws1l, wn1h, wn1l,
                                          (float*)0, N, 0, 4, R_Y, R_Z, (float*)0);
  k_aggfuse<<<N / 4, 256, 0, stream>>>(R_Y, R_Z, offs, csr, b1f, 1, R_H);

  // ---- Layer 2 (no relu) ----
  gemm_packed<<<MT * 4, 256, 0, stream>>>(R_H, DH, ws2h, ws2l, wn2h, wn2l,
                                          (float*)0, N, 0, 4, R_Y, R_Z, (float*)0);
  k_aggfuse<<<N / 4, 256, 0, stream>>>(R_Y, R_Z, offs, csr, b2f, 0, R_H);

  // ---- Predictor: 4 chunks of 50000 pairs (H = R_H) ----
  const int PC = 50000;
  const int G_P = CDIV(PC, 128) * 2;
  for (int c = 0; c < 4; ++c) {
    int base = c * PC;
    k_egatherw<<<PC / 4, 256, 0, stream>>>(R_H, psrc, pdst, nsrc, ndst, base, P, R_Y);
    // Z1 = relu(E@Wp1 + bp1): R_Y -> R_Z (packed)
    gemm_packed<<<G_P, 256, 0, stream>>>(R_Y, DH, wp1h, wp1l,
                                         (unsigned short*)0, (unsigned short*)0,
                                         bp1f, PC, 1, 2, R_Z, (unsigned int*)0, (float*)0);
    // Z2 = relu(Z1@Wp2 + bp2): R_Z -> Z2f (fp32 in R_Y; E dead)
    gemm_packed<<<G_P, 256, 0, stream>>>(R_Z, DH, wp2h, wp2l,
                                         (unsigned short*)0, (unsigned short*)0,
                                         bp2f, PC, 1, 2, (unsigned int*)0, (unsigned int*)0, Z2f);
    k_finaldot<<<CDIV(PC, 4), 256, 0, stream>>>(Z2f, wp3f, bp3f, d_out, base, PC, flagp);
  }
}

// Round 9
// 1248.820 us; speedup vs baseline: 1.2184x; 1.2184x over previous
//
#include <hip/hip_runtime.h>
#include <hip/hip_bf16.h>

#define CDIV(a, b) (((a) + (b) - 1) / (b))

typedef __attribute__((ext_vector_type(8))) __bf16 bf16x8;
typedef __attribute__((ext_vector_type(4))) float f32x4;

__device__ __forceinline__ float bf2f(unsigned short u) {
  union { unsigned int i; float f; } c; c.i = ((unsigned int)u) << 16; return c.f;
}
__device__ __forceinline__ unsigned short f2bf(float f) {
  union { float f; unsigned int i; } c; c.f = f;
  unsigned int r = c.i + 0x7fffu + ((c.i >> 16) & 1u);
  return (unsigned short)(r >> 16);
}
// packed hi/lo (u32 = hi | lo<<16)
__device__ __forceinline__ float dec1(unsigned int u) {
  union { unsigned int i; float f; } a, b;
  a.i = u << 16; b.i = u & 0xffff0000u;
  return a.f + b.f;
}
__device__ __forceinline__ unsigned int packhl(float v) {
  unsigned short h = f2bf(v);
  unsigned short l = f2bf(v - bf2f(h));
  return (unsigned int)h | ((unsigned int)l << 16);
}

// ---- dtype detector: flag=1 if fp32 storage, 0 if bf16 storage ----
__global__ void k_detect(const unsigned short* __restrict__ xq, int nsamp, int* __restrict__ flagp) {
  __shared__ float sm[256];
  int t = threadIdx.x;
  float mx = 0.f;
  for (int i = t; i < nsamp; i += 256) {
    float v = bf2f(xq[i]);
    if (!(v == v)) v = 1e30f;
    mx = fmaxf(mx, fabsf(v));
  }
  sm[t] = mx; __syncthreads();
  for (int o = 128; o > 0; o >>= 1) {
    if (t < o) sm[t] = fmaxf(sm[t], sm[t + o]);
    __syncthreads();
  }
  if (t == 0) *flagp = (sm[0] > 1e6f) ? 1 : 0;
}

// ---- 7 small fp32 conversions in one dispatch (block b -> buffer b) ----
__global__ void k_cvt7(const void* p0, const void* p1, const void* p2, const void* p3,
                       const void* p4, const void* p5, const void* p6,
                       float* d0, float* d1, float* d2, float* d3,
                       float* d4, float* d5, float* d6, const int* __restrict__ flagp) {
  int b = blockIdx.x, t = threadIdx.x;
  const void* s = 0; float* d = 0; int n = 256;
  switch (b) {
    case 0: s = p0; d = d0; break;
    case 1: s = p1; d = d1; break;
    case 2: s = p2; d = d2; break;
    case 3: s = p3; d = d3; break;
    case 4: s = p4; d = d4; break;
    case 5: s = p5; d = d5; break;
    default: s = p6; d = d6; n = 1; break;
  }
  if (t < n) d[t] = (*flagp) ? ((const float*)s)[t] : bf2f(((const unsigned short*)s)[t]);
}

// ---- weight: W[K,256] -> transposed bf16-hi Bt[256,K] ----
__global__ void k_wh(const void* __restrict__ W, unsigned short* __restrict__ Bth,
                     int K, const int* __restrict__ flagp) {
  int i = blockIdx.x * 256 + threadIdx.x;
  if (i >= K * 256) return;
  int k = i >> 8, n = i & 255;
  float v = (*flagp) ? ((const float*)W)[i] : bf2f(((const unsigned short*)W)[i]);
  Bth[(size_t)n * K + k] = f2bf(v);
}

// ---- x -> packed hi/lo u32 ----
__global__ void k_splitpack(const void* __restrict__ x, unsigned int* __restrict__ Xp, int n,
                            const int* __restrict__ flagp) {
  int i = blockIdx.x * 256 + threadIdx.x;
  if (i >= n) return;
  float v = (*flagp) ? ((const float*)x)[i] : bf2f(((const unsigned short*)x)[i]);
  Xp[i] = packhl(v);
}

__global__ void k_zero_i32(int* p, int n) {
  int i = blockIdx.x * 256 + threadIdx.x;
  if (i < n) p[i] = 0;
}

// ---------------- CSR build ----------------
__global__ void k_deg(const int* __restrict__ dst, int* __restrict__ deg, int E) {
  int e = blockIdx.x * 256 + threadIdx.x;
  if (e < E) atomicAdd(&deg[dst[e]], 1);
}
__global__ void k_scan1(const int* __restrict__ in, int* __restrict__ out, int* __restrict__ bsums, int n) {
  __shared__ int sh[256];
  int t = threadIdx.x, i = blockIdx.x * 256 + t;
  int v = (i < n) ? in[i] : 0;
  sh[t] = v; __syncthreads();
  for (int o = 1; o < 256; o <<= 1) {
    int add = (t >= o) ? sh[t - o] : 0;
    __syncthreads();
    sh[t] += add;
    __syncthreads();
  }
  if (i < n) out[i] = sh[t] - v;
  if (t == 255) bsums[blockIdx.x] = sh[255];
}
__global__ void k_scan2(int* bsums, int nb) {
  __shared__ int sh[256];
  int t = threadIdx.x;
  int v = (t < nb) ? bsums[t] : 0;
  sh[t] = v; __syncthreads();
  for (int o = 1; o < 256; o <<= 1) {
    int add = (t >= o) ? sh[t - o] : 0;
    __syncthreads();
    sh[t] += add;
    __syncthreads();
  }
  if (t < nb) bsums[t] = sh[t] - v;
}
__global__ void k_scan3(int* offs, const int* bsums, int n, int etot) {
  int i = blockIdx.x * 256 + threadIdx.x;
  if (i < n) offs[i] += bsums[blockIdx.x];
  if (i == 0) offs[n] = etot;
}
__global__ void k_copy_i32(const int* __restrict__ a, int* __restrict__ b, int n) {
  int i = blockIdx.x * 256 + threadIdx.x;
  if (i < n) b[i] = a[i];
}
__global__ void k_fill(const int* __restrict__ dst, const int* __restrict__ src,
                       int* __restrict__ cursor, int* __restrict__ csr_src, int E) {
  int e = blockIdx.x * 256 + threadIdx.x;
  if (e >= E) return;
  int pos = atomicAdd(&cursor[dst[e]], 1);
  csr_src[pos] = src[e];
}
__global__ void k_sortcsr(const int* __restrict__ offs, int* __restrict__ csr, int n) {
  int v = blockIdx.x * 256 + threadIdx.x;
  if (v >= n) return;
  int s = offs[v], e = offs[v + 1];
  for (int i = s + 1; i < e; ++i) {
    int key = csr[i];
    int j = i - 1;
    while (j >= s && csr[j] > key) { csr[j + 1] = csr[j]; --j; }
    csr[j + 1] = key;
  }
}

// ---- fused agg epilogue: H[v] = act(Y[v] + mean_{u} Z[u] + b); Z is bf16 plane ----
// one wave per node, lane handles 4 cols. grid = N/4, block 256.
__global__ void k_aggfuse(const unsigned int* __restrict__ Yp, const unsigned short* __restrict__ Zh,
                          const int* __restrict__ offs, const int* __restrict__ csr,
                          const float* __restrict__ bias, int relu,
                          unsigned int* __restrict__ Hp) {
  int w = threadIdx.x >> 6, lane = threadIdx.x & 63;
  int v = blockIdx.x * 4 + w;
  int c4 = lane * 4;
  uint4 yq = *(const uint4*)&Yp[(size_t)v * 256 + c4];
  int s = offs[v], e = offs[v + 1];
  float a0 = 0.f, a1 = 0.f, a2 = 0.f, a3 = 0.f;
  int i = s;
  for (; i + 2 <= e; i += 2) {
    uint2 z0 = *(const uint2*)&Zh[(size_t)csr[i] * 256 + c4];
    uint2 z1 = *(const uint2*)&Zh[(size_t)csr[i + 1] * 256 + c4];
    a0 += bf2f((unsigned short)z0.x) + bf2f((unsigned short)z1.x);
    a1 += bf2f((unsigned short)(z0.x >> 16)) + bf2f((unsigned short)(z1.x >> 16));
    a2 += bf2f((unsigned short)z0.y) + bf2f((unsigned short)z1.y);
    a3 += bf2f((unsigned short)(z0.y >> 16)) + bf2f((unsigned short)(z1.y >> 16));
  }
  if (i < e) {
    uint2 z0 = *(const uint2*)&Zh[(size_t)csr[i] * 256 + c4];
    a0 += bf2f((unsigned short)z0.x);
    a1 += bf2f((unsigned short)(z0.x >> 16));
    a2 += bf2f((unsigned short)z0.y);
    a3 += bf2f((unsigned short)(z0.y >> 16));
  }
  float inv = 1.f / fmaxf((float)(e - s), 1.f);
  float4 bv = *(const float4*)&bias[c4];
  float r0 = dec1(yq.x) + a0 * inv + bv.x;
  float r1 = dec1(yq.y) + a1 * inv + bv.y;
  float r2 = dec1(yq.z) + a2 * inv + bv.z;
  float r3 = dec1(yq.w) + a3 * inv + bv.w;
  if (relu) {
    r0 = fmaxf(r0, 0.f); r1 = fmaxf(r1, 0.f);
    r2 = fmaxf(r2, 0.f); r3 = fmaxf(r3, 0.f);
  }
  uint4 o;
  o.x = packhl(r0); o.y = packhl(r1); o.z = packhl(r2); o.w = packhl(r3);
  *(uint4*)&Hp[(size_t)v * 256 + c4] = o;
}

// ---- predictor edge features: E[p] = H[s]*H[d]; one wave per pair ----
__global__ void k_egatherw(const unsigned int* __restrict__ Hp,
                           const int* __restrict__ ps, const int* __restrict__ pd,
                           const int* __restrict__ ns, const int* __restrict__ nd,
                           int base, int nPos, unsigned int* __restrict__ Ep) {
  int w = threadIdx.x >> 6, lane = threadIdx.x & 63;
  int p = blockIdx.x * 4 + w;
  int g = base + p;
  int s, d;
  if (g < nPos) { s = ps[g]; d = pd[g]; }
  else          { s = ns[g - nPos]; d = nd[g - nPos]; }
  int c4 = lane * 4;
  uint4 aq = *(const uint4*)&Hp[(size_t)s * 256 + c4];
  uint4 bq = *(const uint4*)&Hp[(size_t)d * 256 + c4];
  uint4 o;
  o.x = packhl(dec1(aq.x) * dec1(bq.x));
  o.y = packhl(dec1(aq.y) * dec1(bq.y));
  o.z = packhl(dec1(aq.z) * dec1(bq.z));
  o.w = packhl(dec1(aq.w) * dec1(bq.w));
  *(uint4*)&Ep[(size_t)p * 256 + c4] = o;
}

// ---- MFMA GEMM: A packed u32 (exact), B bf16-hi only (2-product split) ----
// nsel=4: nt 0,1 -> B1/O1 (packed or fp32); nt 2,3 -> B2/O2b (bf16 plane).
// nsel=2: nt 0,1 -> B1/O1. grid.x = CDIV(M,128)*nsel, block 256.
__global__ __launch_bounds__(256) void gemm2(
    const unsigned int* __restrict__ Ap, int K,
    const unsigned short* __restrict__ B1h, const unsigned short* __restrict__ B2h,
    int M, int nsel, int relu1, const float* __restrict__ bias1,
    unsigned int* __restrict__ O1p, float* __restrict__ O1f,
    unsigned short* __restrict__ O2b) {
  __shared__ unsigned short sAh[128 * 40], sAl[128 * 40], sBh[128 * 40];
  int t = threadIdx.x;
  int mt = blockIdx.x / nsel, nt = blockIdx.x % nsel;
  int m0 = mt * 128;
  const unsigned short* Bh = (nt < 2) ? B1h : B2h;
  int n0 = (nt & 1) * 128;
  int wid = t >> 6, lane = t & 63;
  int wr = (wid >> 1) * 64, wc = (wid & 1) * 64;
  int quad = lane >> 4, lrow = lane & 15;

  f32x4 acc[4][4];
  const f32x4 z4 = {0.f, 0.f, 0.f, 0.f};
#pragma unroll
  for (int i = 0; i < 4; ++i)
#pragma unroll
    for (int j = 0; j < 4; ++j) acc[i][j] = z4;

  int sr = t >> 2;          // staging row 0..63 (+64 on rep 1)
  int c8 = (t & 3) * 8;     // staging col 0,8,16,24

  for (int k0 = 0; k0 < K; k0 += 32) {
#pragma unroll
    for (int rep = 0; rep < 2; ++rep) {
      int r = sr + rep * 64;
      int arow = m0 + r; if (arow >= M) arow = M - 1;
      const unsigned int* ap = &Ap[(size_t)arow * K + k0 + c8];
      uint4 q0 = *(const uint4*)ap;
      uint4 q1 = *(const uint4*)(ap + 4);
      uint4 ubh = *(const uint4*)&Bh[(size_t)(n0 + r) * K + k0 + c8];
      uint4 hh, ll;
      hh.x = (q0.x & 0xffffu) | (q0.y << 16);
      hh.y = (q0.z & 0xffffu) | (q0.w << 16);
      hh.z = (q1.x & 0xffffu) | (q1.y << 16);
      hh.w = (q1.z & 0xffffu) | (q1.w << 16);
      ll.x = (q0.x >> 16) | (q0.y & 0xffff0000u);
      ll.y = (q0.z >> 16) | (q0.w & 0xffff0000u);
      ll.z = (q1.x >> 16) | (q1.y & 0xffff0000u);
      ll.w = (q1.z >> 16) | (q1.w & 0xffff0000u);
      *(uint4*)&sAh[r * 40 + c8] = hh;
      *(uint4*)&sAl[r * 40 + c8] = ll;
      *(uint4*)&sBh[r * 40 + c8] = ubh;
    }
    __syncthreads();
    bf16x8 ah[4], al[4], bh[4];
#pragma unroll
    for (int i = 0; i < 4; ++i) {
      int ar = (wr + i * 16 + lrow) * 40 + quad * 8;
      int br = (wc + i * 16 + lrow) * 40 + quad * 8;
      ah[i] = *(const bf16x8*)&sAh[ar];
      al[i] = *(const bf16x8*)&sAl[ar];
      bh[i] = *(const bf16x8*)&sBh[br];
    }
#pragma unroll
    for (int i = 0; i < 4; ++i)
#pragma unroll
      for (int j = 0; j < 4; ++j) {
        acc[i][j] = __builtin_amdgcn_mfma_f32_16x16x32_bf16(ah[i], bh[j], acc[i][j], 0, 0, 0);
        acc[i][j] = __builtin_amdgcn_mfma_f32_16x16x32_bf16(al[i], bh[j], acc[i][j], 0, 0, 0);
      }
    __syncthreads();
  }

  // epilogue: C/D layout col = lane&15, row = (lane>>4)*4 + reg
#pragma unroll
  for (int j = 0; j < 4; ++j) {
    int gc = n0 + wc + j * 16 + lrow;
    float bv = (nt < 2 && bias1) ? bias1[gc] : 0.f;
#pragma unroll
    for (int i = 0; i < 4; ++i) {
#pragma unroll
      for (int rr = 0; rr < 4; ++rr) {
        int gr = m0 + wr + i * 16 + quad * 4 + rr;
        if (gr < M) {
          float v = acc[i][j][rr] + bv;
          size_t idx = (size_t)gr * 256 + gc;
          if (nt < 2) {
            if (relu1) v = fmaxf(v, 0.f);
            if (O1f) O1f[idx] = v;
            else     O1p[idx] = packhl(v);
          } else {
            O2b[idx] = f2bf(v);
          }
        }
      }
    }
  }
}

// ---- final 256->1 dot ----
__global__ void k_finaldot(const float* __restrict__ Z2, const float* __restrict__ wp3,
                           const float* __restrict__ bp3, void* __restrict__ out,
                           int base, int Pc, const int* __restrict__ flagp) {
  int wid = threadIdx.x >> 6, lane = threadIdx.x & 63;
  int p = blockIdx.x * 4 + wid;
  if (p >= Pc) return;
  float4 zv = *(const float4*)&Z2[(size_t)p * 256 + lane * 4];
  float s = zv.x * wp3[lane * 4 + 0] + zv.y * wp3[lane * 4 + 1] +
            zv.z * wp3[lane * 4 + 2] + zv.w * wp3[lane * 4 + 3];
#pragma unroll
  for (int o = 32; o >= 1; o >>= 1) s += __shfl_xor(s, o, 64);
  if (lane == 0) {
    float r = s + bp3[0];
    if (*flagp) ((float*)out)[base + p] = r;
    else        ((unsigned short*)out)[base + p] = f2bf(r);
  }
}

extern "C" void kernel_launch(void* const* d_in, const int* in_sizes, int n_in,
                              void* d_out, int out_size, void* d_ws, size_t ws_size,
                              hipStream_t stream) {
  const int N = 50000, E = 800000, P = 100000, DIN = 128, DH = 256;
  const void* x = d_in[0];
  const int* esrc = (const int*)d_in[1];
  const int* edst = (const int*)d_in[2];
  const int* psrc = (const int*)d_in[3];
  const int* pdst = (const int*)d_in[4];
  const int* nsrc = (const int*)d_in[5];
  const int* ndst = (const int*)d_in[6];
  const void* Ws0 = d_in[7];  const void* Wn0 = d_in[8];  const void* b0 = d_in[9];
  const void* Ws1 = d_in[10]; const void* Wn1 = d_in[11]; const void* b1 = d_in[12];
  const void* Ws2 = d_in[13]; const void* Wn2 = d_in[14]; const void* b2 = d_in[15];
  const void* Wp1 = d_in[16]; const void* bp1 = d_in[17];
  const void* Wp2 = d_in[18]; const void* bp2 = d_in[19];
  const void* Wp3 = d_in[20]; const void* bp3 = d_in[21];
  (void)in_sizes; (void)n_in; (void)out_size; (void)ws_size;

  // ---- workspace: three regions (u32 [N,256] capacity each) ----
  const size_t NH = (size_t)N * DH;               // 12,800,000
  unsigned int* R_H = (unsigned int*)d_ws;        // H packed / Xp(L0)
  unsigned int* R_Y = R_H + NH;                   // Y packed / E packed / Z2 fp32
  unsigned int* R_Z = R_Y + NH;                   // Zh bf16 plane (layers) / Z1 packed (pred)
  unsigned short* Zh = (unsigned short*)R_Z;
  unsigned short* W16 = (unsigned short*)(R_Z + NH);
  unsigned short* ws0h = W16;                     // K=128: 32768 each
  unsigned short* wn0h = ws0h + 32768;
  unsigned short* ws1h = wn0h + 32768;            // K=256: 65536 each
  unsigned short* wn1h = ws1h + 65536;
  unsigned short* ws2h = wn1h + 65536;
  unsigned short* wn2h = ws2h + 65536;
  unsigned short* wp1h = wn2h + 65536;
  unsigned short* wp2h = wp1h + 65536;
  float* FB = (float*)(wp2h + 65536);
  float* b0f  = FB;
  float* b1f  = b0f + 256;
  float* b2f  = b1f + 256;
  float* bp1f = b2f + 256;
  float* bp2f = bp1f + 256;
  float* wp3f = bp2f + 256;
  float* bp3f = wp3f + 256;
  int* deg   = (int*)(bp3f + 4);
  int* offs  = deg + N;
  int* cur   = offs + (N + 1);
  int* bsums = cur + N;
  int* csr   = bsums + 256;
  int* flagp = csr + E;
  // total ~158 MB

  unsigned int* Xp = R_H;                 // [N,128] packed (layer-0 A)
  float* Z2f = (float*)R_Y;               // predictor Z2 fp32

  // ---- dtype detection ----
  k_detect<<<1, 256, 0, stream>>>((const unsigned short*)x, 8192, flagp);

  // ---- weight hi-transpose + small cvts ----
  k_wh<<<CDIV(DIN * DH, 256), 256, 0, stream>>>(Ws0, ws0h, DIN, flagp);
  k_wh<<<CDIV(DIN * DH, 256), 256, 0, stream>>>(Wn0, wn0h, DIN, flagp);
  k_wh<<<CDIV(DH * DH, 256), 256, 0, stream>>>(Ws1, ws1h, DH, flagp);
  k_wh<<<CDIV(DH * DH, 256), 256, 0, stream>>>(Wn1, wn1h, DH, flagp);
  k_wh<<<CDIV(DH * DH, 256), 256, 0, stream>>>(Ws2, ws2h, DH, flagp);
  k_wh<<<CDIV(DH * DH, 256), 256, 0, stream>>>(Wn2, wn2h, DH, flagp);
  k_wh<<<CDIV(DH * DH, 256), 256, 0, stream>>>(Wp1, wp1h, DH, flagp);
  k_wh<<<CDIV(DH * DH, 256), 256, 0, stream>>>(Wp2, wp2h, DH, flagp);
  k_cvt7<<<7, 256, 0, stream>>>(b0, b1, b2, bp1, bp2, Wp3, bp3,
                                b0f, b1f, b2f, bp1f, bp2f, wp3f, bp3f, flagp);

  // ---- CSR build (deterministic: sorted adjacency) ----
  int nb = CDIV(N, 256);
  k_zero_i32<<<nb, 256, 0, stream>>>(deg, N);
  k_deg<<<CDIV(E, 256), 256, 0, stream>>>(edst, deg, E);
  k_scan1<<<nb, 256, 0, stream>>>(deg, offs, bsums, N);
  k_scan2<<<1, 256, 0, stream>>>(bsums, nb);
  k_scan3<<<nb, 256, 0, stream>>>(offs, bsums, N, E);
  k_copy_i32<<<nb, 256, 0, stream>>>(offs, cur, N);
  k_fill<<<CDIV(E, 256), 256, 0, stream>>>(edst, esrc, cur, csr, E);
  k_sortcsr<<<nb, 256, 0, stream>>>(offs, csr, N);

  const int MT = CDIV(N, 128);          // 391

  // ---- Layer 0: Y=x@Ws0 (packed), Zh=x@Wn0 (bf16); H = relu(Y + agg(Zh) + b0) ----
  k_splitpack<<<CDIV(N * DIN, 256), 256, 0, stream>>>(x, Xp, N * DIN, flagp);
  gemm2<<<MT * 4, 256, 0, stream>>>(Xp, DIN, ws0h, wn0h, N, 4, 0, (float*)0,
                                    R_Y, (float*)0, Zh);
  k_aggfuse<<<N / 4, 256, 0, stream>>>(R_Y, Zh, offs, csr, b0f, 1, R_H);

  // ---- Layer 1 ----
  gemm2<<<MT * 4, 256, 0, stream>>>(R_H, DH, ws1h, wn1h, N, 4, 0, (float*)0,
                                    R_Y, (float*)0, Zh);
  k_aggfuse<<<N / 4, 256, 0, stream>>>(R_Y, Zh, offs, csr, b1f, 1, R_H);

  // ---- Layer 2 (no relu) ----
  gemm2<<<MT * 4, 256, 0, stream>>>(R_H, DH, ws2h, wn2h, N, 4, 0, (float*)0,
                                    R_Y, (float*)0, Zh);
  k_aggfuse<<<N / 4, 256, 0, stream>>>(R_Y, Zh, offs, csr, b2f, 0, R_H);

  // ---- Predictor: 4 chunks of 50000 pairs ----
  const int PC = 50000;
  const int G_P = CDIV(PC, 128) * 2;
  for (int c = 0; c < 4; ++c) {
    int base = c * PC;
    k_egatherw<<<PC / 4, 256, 0, stream>>>(R_H, psrc, pdst, nsrc, ndst, base, P, R_Y);
    // Z1 = relu(E@Wp1 + bp1): R_Y -> R_Z packed
    gemm2<<<G_P, 256, 0, stream>>>(R_Y, DH, wp1h, (unsigned short*)0, PC, 2, 1, bp1f,
                                   R_Z, (float*)0, (unsigned short*)0);
    // Z2 = relu(Z1@Wp2 + bp2): R_Z -> Z2f (fp32 in R_Y; E dead)
    gemm2<<<G_P, 256, 0, stream>>>(R_Z, DH, wp2h, (unsigned short*)0, PC, 2, 1, bp2f,
                                   (unsigned int*)0, Z2f, (unsigned short*)0);
    k_finaldot<<<CDIV(PC, 4), 256, 0, stream>>>(Z2f, wp3f, bp3f, d_out, base, PC, flagp);
  }
}

// Round 10
// 1128.260 us; speedup vs baseline: 1.3486x; 1.1069x over previous
//
#include <hip/hip_runtime.h>
#include <hip/hip_bf16.h>

#define CDIV(a, b) (((a) + (b) - 1) / (b))

typedef __attribute__((ext_vector_type(8))) __bf16 bf16x8;
typedef __attribute__((ext_vector_type(4))) float f32x4;

__device__ __forceinline__ float bf2f(unsigned short u) {
  union { unsigned int i; float f; } c; c.i = ((unsigned int)u) << 16; return c.f;
}
__device__ __forceinline__ unsigned short f2bf(float f) {
  union { float f; unsigned int i; } c; c.f = f;
  unsigned int r = c.i + 0x7fffu + ((c.i >> 16) & 1u);
  return (unsigned short)(r >> 16);
}
// packed hi/lo (u32 = hi | lo<<16)
__device__ __forceinline__ float dec1(unsigned int u) {
  union { unsigned int i; float f; } a, b;
  a.i = u << 16; b.i = u & 0xffff0000u;
  return a.f + b.f;
}
__device__ __forceinline__ unsigned int packhl(float v) {
  unsigned short h = f2bf(v);
  unsigned short l = f2bf(v - bf2f(h));
  return (unsigned int)h | ((unsigned int)l << 16);
}

// ---- dtype detector: flag=1 if fp32 storage, 0 if bf16 storage ----
__global__ void k_detect(const unsigned short* __restrict__ xq, int nsamp, int* __restrict__ flagp) {
  __shared__ float sm[256];
  int t = threadIdx.x;
  float mx = 0.f;
  for (int i = t; i < nsamp; i += 256) {
    float v = bf2f(xq[i]);
    if (!(v == v)) v = 1e30f;
    mx = fmaxf(mx, fabsf(v));
  }
  sm[t] = mx; __syncthreads();
  for (int o = 128; o > 0; o >>= 1) {
    if (t < o) sm[t] = fmaxf(sm[t], sm[t + o]);
    __syncthreads();
  }
  if (t == 0) *flagp = (sm[0] > 1e6f) ? 1 : 0;
}

// ---- 7 small fp32 conversions in one dispatch ----
__global__ void k_cvt7(const void* p0, const void* p1, const void* p2, const void* p3,
                       const void* p4, const void* p5, const void* p6,
                       float* d0, float* d1, float* d2, float* d3,
                       float* d4, float* d5, float* d6, const int* __restrict__ flagp) {
  int b = blockIdx.x, t = threadIdx.x;
  const void* s = 0; float* d = 0; int n = 256;
  switch (b) {
    case 0: s = p0; d = d0; break;
    case 1: s = p1; d = d1; break;
    case 2: s = p2; d = d2; break;
    case 3: s = p3; d = d3; break;
    case 4: s = p4; d = d4; break;
    case 5: s = p5; d = d5; break;
    default: s = p6; d = d6; n = 1; break;
  }
  if (t < n) d[t] = (*flagp) ? ((const float*)s)[t] : bf2f(((const unsigned short*)s)[t]);
}

// ---- weight: W[K,256] -> transposed bf16-hi Bt[256,K] ----
__global__ void k_wh(const void* __restrict__ W, unsigned short* __restrict__ Bth,
                     int K, const int* __restrict__ flagp) {
  int i = blockIdx.x * 256 + threadIdx.x;
  if (i >= K * 256) return;
  int k = i >> 8, n = i & 255;
  float v = (*flagp) ? ((const float*)W)[i] : bf2f(((const unsigned short*)W)[i]);
  Bth[(size_t)n * K + k] = f2bf(v);
}

// ---- x -> packed hi/lo u32 ----
__global__ void k_splitpack(const void* __restrict__ x, unsigned int* __restrict__ Xp, int n,
                            const int* __restrict__ flagp) {
  int i = blockIdx.x * 256 + threadIdx.x;
  if (i >= n) return;
  float v = (*flagp) ? ((const float*)x)[i] : bf2f(((const unsigned short*)x)[i]);
  Xp[i] = packhl(v);
}

__global__ void k_zero_i32(int* p, int n) {
  int i = blockIdx.x * 256 + threadIdx.x;
  if (i < n) p[i] = 0;
}

// ---------------- CSR build ----------------
__global__ void k_deg(const int* __restrict__ dst, int* __restrict__ deg, int E) {
  int e = blockIdx.x * 256 + threadIdx.x;
  if (e < E) atomicAdd(&deg[dst[e]], 1);
}
__global__ void k_scan1(const int* __restrict__ in, int* __restrict__ out, int* __restrict__ bsums, int n) {
  __shared__ int sh[256];
  int t = threadIdx.x, i = blockIdx.x * 256 + t;
  int v = (i < n) ? in[i] : 0;
  sh[t] = v; __syncthreads();
  for (int o = 1; o < 256; o <<= 1) {
    int add = (t >= o) ? sh[t - o] : 0;
    __syncthreads();
    sh[t] += add;
    __syncthreads();
  }
  if (i < n) out[i] = sh[t] - v;
  if (t == 255) bsums[blockIdx.x] = sh[255];
}
__global__ void k_scan2(int* bsums, int nb) {
  __shared__ int sh[256];
  int t = threadIdx.x;
  int v = (t < nb) ? bsums[t] : 0;
  sh[t] = v; __syncthreads();
  for (int o = 1; o < 256; o <<= 1) {
    int add = (t >= o) ? sh[t - o] : 0;
    __syncthreads();
    sh[t] += add;
    __syncthreads();
  }
  if (t < nb) bsums[t] = sh[t] - v;
}
__global__ void k_scan3(int* offs, const int* bsums, int n, int etot) {
  int i = blockIdx.x * 256 + threadIdx.x;
  if (i < n) offs[i] += bsums[blockIdx.x];
  if (i == 0) offs[n] = etot;
}
__global__ void k_copy_i32(const int* __restrict__ a, int* __restrict__ b, int n) {
  int i = blockIdx.x * 256 + threadIdx.x;
  if (i < n) b[i] = a[i];
}
__global__ void k_fill(const int* __restrict__ dst, const int* __restrict__ src,
                       int* __restrict__ cursor, int* __restrict__ csr_src, int E) {
  int e = blockIdx.x * 256 + threadIdx.x;
  if (e >= E) return;
  int pos = atomicAdd(&cursor[dst[e]], 1);
  csr_src[pos] = src[e];
}
// ---- wave-parallel bitonic sort per node (deterministic adjacency order) ----
__global__ void k_sortw(const int* __restrict__ offs, int* __restrict__ csr, int n) {
  int w = threadIdx.x >> 6, lane = threadIdx.x & 63;
  int v = blockIdx.x * 4 + w;
  if (v >= n) return;
  int s = offs[v], e = offs[v + 1];
  int deg = e - s;
  if (deg <= 1) return;
  if (deg > 64) {                       // astronomically rare (Poisson(16)); serial fallback
    if (lane == 0) {
      for (int i = s + 1; i < e; ++i) {
        int key = csr[i], j = i - 1;
        while (j >= s && csr[j] > key) { csr[j + 1] = csr[j]; --j; }
        csr[j + 1] = key;
      }
    }
    return;
  }
  int val = (lane < deg) ? csr[s + lane] : 0x7fffffff;
#pragma unroll
  for (int k = 2; k <= 64; k <<= 1) {
    bool dir = (lane & k) == 0;
#pragma unroll
    for (int j = k >> 1; j > 0; j >>= 1) {
      int p = __shfl_xor(val, j, 64);
      bool lower = (lane & j) == 0;
      val = (lower == dir) ? min(val, p) : max(val, p);
    }
  }
  if (lane < deg) csr[s + lane] = val;
}

// ---- fused agg epilogue: H[v] = act(Y[v] + mean_{u} Z[u] + b); Z is bf16 plane ----
__global__ void k_aggfuse(const unsigned int* __restrict__ Yp, const unsigned short* __restrict__ Zh,
                          const int* __restrict__ offs, const int* __restrict__ csr,
                          const float* __restrict__ bias, int relu,
                          unsigned int* __restrict__ Hp) {
  int w = threadIdx.x >> 6, lane = threadIdx.x & 63;
  int v = blockIdx.x * 4 + w;
  int c4 = lane * 4;
  uint4 yq = *(const uint4*)&Yp[(size_t)v * 256 + c4];
  int s = offs[v], e = offs[v + 1];
  float a0 = 0.f, a1 = 0.f, a2 = 0.f, a3 = 0.f;
  int i = s;
  for (; i + 2 <= e; i += 2) {
    uint2 z0 = *(const uint2*)&Zh[(size_t)csr[i] * 256 + c4];
    uint2 z1 = *(const uint2*)&Zh[(size_t)csr[i + 1] * 256 + c4];
    a0 += bf2f((unsigned short)z0.x) + bf2f((unsigned short)z1.x);
    a1 += bf2f((unsigned short)(z0.x >> 16)) + bf2f((unsigned short)(z1.x >> 16));
    a2 += bf2f((unsigned short)z0.y) + bf2f((unsigned short)z1.y);
    a3 += bf2f((unsigned short)(z0.y >> 16)) + bf2f((unsigned short)(z1.y >> 16));
  }
  if (i < e) {
    uint2 z0 = *(const uint2*)&Zh[(size_t)csr[i] * 256 + c4];
    a0 += bf2f((unsigned short)z0.x);
    a1 += bf2f((unsigned short)(z0.x >> 16));
    a2 += bf2f((unsigned short)z0.y);
    a3 += bf2f((unsigned short)(z0.y >> 16));
  }
  float inv = 1.f / fmaxf((float)(e - s), 1.f);
  float4 bv = *(const float4*)&bias[c4];
  float r0 = dec1(yq.x) + a0 * inv + bv.x;
  float r1 = dec1(yq.y) + a1 * inv + bv.y;
  float r2 = dec1(yq.z) + a2 * inv + bv.z;
  float r3 = dec1(yq.w) + a3 * inv + bv.w;
  if (relu) {
    r0 = fmaxf(r0, 0.f); r1 = fmaxf(r1, 0.f);
    r2 = fmaxf(r2, 0.f); r3 = fmaxf(r3, 0.f);
  }
  uint4 o;
  o.x = packhl(r0); o.y = packhl(r1); o.z = packhl(r2); o.w = packhl(r3);
  *(uint4*)&Hp[(size_t)v * 256 + c4] = o;
}

// ---- MFMA GEMM: A packed u32 (exact), B bf16-hi (2-product). ----
// nsel=4: nt 0,1 -> B1/out1; nt 2,3 -> B2/O2b (bf16). nsel=2: B1/out1 only.
// out1: O1p packed, else O1b bf16. grid.x = CDIV(M,128)*nsel.
__global__ __launch_bounds__(256) void gemm2(
    const unsigned int* __restrict__ Ap, int K,
    const unsigned short* __restrict__ B1h, const unsigned short* __restrict__ B2h,
    int M, int nsel, int relu1, const float* __restrict__ bias1,
    unsigned int* __restrict__ O1p, unsigned short* __restrict__ O1b,
    unsigned short* __restrict__ O2b) {
  __shared__ unsigned short sAh[128 * 40], sAl[128 * 40], sBh[128 * 40];
  int t = threadIdx.x;
  int mt = blockIdx.x / nsel, nt = blockIdx.x % nsel;
  int m0 = mt * 128;
  const unsigned short* Bh = (nt < 2) ? B1h : B2h;
  int n0 = (nt & 1) * 128;
  int wid = t >> 6, lane = t & 63;
  int wr = (wid >> 1) * 64, wc = (wid & 1) * 64;
  int quad = lane >> 4, lrow = lane & 15;

  f32x4 acc[4][4];
  const f32x4 z4 = {0.f, 0.f, 0.f, 0.f};
#pragma unroll
  for (int i = 0; i < 4; ++i)
#pragma unroll
    for (int j = 0; j < 4; ++j) acc[i][j] = z4;

  int sr = t >> 2;
  int c8 = (t & 3) * 8;

  for (int k0 = 0; k0 < K; k0 += 32) {
#pragma unroll
    for (int rep = 0; rep < 2; ++rep) {
      int r = sr + rep * 64;
      int arow = m0 + r; if (arow >= M) arow = M - 1;
      const unsigned int* ap = &Ap[(size_t)arow * K + k0 + c8];
      uint4 q0 = *(const uint4*)ap;
      uint4 q1 = *(const uint4*)(ap + 4);
      uint4 ubh = *(const uint4*)&Bh[(size_t)(n0 + r) * K + k0 + c8];
      uint4 hh, ll;
      hh.x = (q0.x & 0xffffu) | (q0.y << 16);
      hh.y = (q0.z & 0xffffu) | (q0.w << 16);
      hh.z = (q1.x & 0xffffu) | (q1.y << 16);
      hh.w = (q1.z & 0xffffu) | (q1.w << 16);
      ll.x = (q0.x >> 16) | (q0.y & 0xffff0000u);
      ll.y = (q0.z >> 16) | (q0.w & 0xffff0000u);
      ll.z = (q1.x >> 16) | (q1.y & 0xffff0000u);
      ll.w = (q1.z >> 16) | (q1.w & 0xffff0000u);
      *(uint4*)&sAh[r * 40 + c8] = hh;
      *(uint4*)&sAl[r * 40 + c8] = ll;
      *(uint4*)&sBh[r * 40 + c8] = ubh;
    }
    __syncthreads();
    bf16x8 ah[4], al[4], bh[4];
#pragma unroll
    for (int i = 0; i < 4; ++i) {
      int ar = (wr + i * 16 + lrow) * 40 + quad * 8;
      int br = (wc + i * 16 + lrow) * 40 + quad * 8;
      ah[i] = *(const bf16x8*)&sAh[ar];
      al[i] = *(const bf16x8*)&sAl[ar];
      bh[i] = *(const bf16x8*)&sBh[br];
    }
#pragma unroll
    for (int i = 0; i < 4; ++i)
#pragma unroll
      for (int j = 0; j < 4; ++j) {
        acc[i][j] = __builtin_amdgcn_mfma_f32_16x16x32_bf16(ah[i], bh[j], acc[i][j], 0, 0, 0);
        acc[i][j] = __builtin_amdgcn_mfma_f32_16x16x32_bf16(al[i], bh[j], acc[i][j], 0, 0, 0);
      }
    __syncthreads();
  }

#pragma unroll
  for (int j = 0; j < 4; ++j) {
    int gc = n0 + wc + j * 16 + lrow;
    float bv = (nt < 2 && bias1) ? bias1[gc] : 0.f;
#pragma unroll
    for (int i = 0; i < 4; ++i) {
#pragma unroll
      for (int rr = 0; rr < 4; ++rr) {
        int gr = m0 + wr + i * 16 + quad * 4 + rr;
        if (gr < M) {
          float v = acc[i][j][rr] + bv;
          size_t idx = (size_t)gr * 256 + gc;
          if (nt < 2) {
            if (relu1) v = fmaxf(v, 0.f);
            if (O1p) O1p[idx] = packhl(v);
            else     O1b[idx] = f2bf(v);
          } else {
            O2b[idx] = f2bf(v);
          }
        }
      }
    }
  }
}

// ---- predictor GEMM-1 with fused edge gather: Z1 = relu((H[s]*H[d])@Wp1^T + b) ----
// A row p: element-wise product of H rows s(p), d(p), hi/lo-split in registers.
// grid.x = CDIV(M,128)*2, block 256.
__global__ __launch_bounds__(256) void gemm_pred1(
    const unsigned int* __restrict__ Hp,
    const int* __restrict__ ps, const int* __restrict__ pd,
    const int* __restrict__ ns, const int* __restrict__ nd,
    int base, int nPos, const unsigned short* __restrict__ Bh,
    const float* __restrict__ bias, int M, unsigned int* __restrict__ O1p) {
  __shared__ unsigned short sAh[128 * 40], sAl[128 * 40], sBh[128 * 40];
  int t = threadIdx.x;
  int mt = blockIdx.x >> 1, nt = blockIdx.x & 1;
  int m0 = mt * 128;
  int n0 = nt * 128;
  int wid = t >> 6, lane = t & 63;
  int wr = (wid >> 1) * 64, wc = (wid & 1) * 64;
  int quad = lane >> 4, lrow = lane & 15;

  f32x4 acc[4][4];
  const f32x4 z4 = {0.f, 0.f, 0.f, 0.f};
#pragma unroll
  for (int i = 0; i < 4; ++i)
#pragma unroll
    for (int j = 0; j < 4; ++j) acc[i][j] = z4;

  int sr = t >> 2;
  int c8 = (t & 3) * 8;

  // resolve the two pair rows this thread stages (rep 0: sr, rep 1: sr+64)
  const unsigned int* Hs[2];
  const unsigned int* Hd[2];
#pragma unroll
  for (int rep = 0; rep < 2; ++rep) {
    int arow = m0 + sr + rep * 64; if (arow >= M) arow = M - 1;
    int g = base + arow;
    int s, d;
    if (g < nPos) { s = ps[g]; d = pd[g]; }
    else          { s = ns[g - nPos]; d = nd[g - nPos]; }
    Hs[rep] = &Hp[(size_t)s * 256];
    Hd[rep] = &Hp[(size_t)d * 256];
  }

  for (int k0 = 0; k0 < 256; k0 += 32) {
#pragma unroll
    for (int rep = 0; rep < 2; ++rep) {
      int r = sr + rep * 64;
      uint4 hs0 = *(const uint4*)(Hs[rep] + k0 + c8);
      uint4 hs1 = *(const uint4*)(Hs[rep] + k0 + c8 + 4);
      uint4 hd0 = *(const uint4*)(Hd[rep] + k0 + c8);
      uint4 hd1 = *(const uint4*)(Hd[rep] + k0 + c8 + 4);
      float e0 = dec1(hs0.x) * dec1(hd0.x);
      float e1 = dec1(hs0.y) * dec1(hd0.y);
      float e2 = dec1(hs0.z) * dec1(hd0.z);
      float e3 = dec1(hs0.w) * dec1(hd0.w);
      float e4 = dec1(hs1.x) * dec1(hd1.x);
      float e5 = dec1(hs1.y) * dec1(hd1.y);
      float e6 = dec1(hs1.z) * dec1(hd1.z);
      float e7 = dec1(hs1.w) * dec1(hd1.w);
      unsigned short h0 = f2bf(e0), h1 = f2bf(e1), h2 = f2bf(e2), h3 = f2bf(e3);
      unsigned short h4 = f2bf(e4), h5 = f2bf(e5), h6 = f2bf(e6), h7 = f2bf(e7);
      uint4 hh, ll;
      hh.x = (unsigned int)h0 | ((unsigned int)h1 << 16);
      hh.y = (unsigned int)h2 | ((unsigned int)h3 << 16);
      hh.z = (unsigned int)h4 | ((unsigned int)h5 << 16);
      hh.w = (unsigned int)h6 | ((unsigned int)h7 << 16);
      ll.x = (unsigned int)f2bf(e0 - bf2f(h0)) | ((unsigned int)f2bf(e1 - bf2f(h1)) << 16);
      ll.y = (unsigned int)f2bf(e2 - bf2f(h2)) | ((unsigned int)f2bf(e3 - bf2f(h3)) << 16);
      ll.z = (unsigned int)f2bf(e4 - bf2f(h4)) | ((unsigned int)f2bf(e5 - bf2f(h5)) << 16);
      ll.w = (unsigned int)f2bf(e6 - bf2f(h6)) | ((unsigned int)f2bf(e7 - bf2f(h7)) << 16);
      *(uint4*)&sAh[r * 40 + c8] = hh;
      *(uint4*)&sAl[r * 40 + c8] = ll;
      *(uint4*)&sBh[r * 40 + c8] = *(const uint4*)&Bh[(size_t)(n0 + r) * 256 + k0 + c8];
    }
    __syncthreads();
    bf16x8 ah[4], al[4], bh[4];
#pragma unroll
    for (int i = 0; i < 4; ++i) {
      int ar = (wr + i * 16 + lrow) * 40 + quad * 8;
      int br = (wc + i * 16 + lrow) * 40 + quad * 8;
      ah[i] = *(const bf16x8*)&sAh[ar];
      al[i] = *(const bf16x8*)&sAl[ar];
      bh[i] = *(const bf16x8*)&sBh[br];
    }
#pragma unroll
    for (int i = 0; i < 4; ++i)
#pragma unroll
      for (int j = 0; j < 4; ++j) {
        acc[i][j] = __builtin_amdgcn_mfma_f32_16x16x32_bf16(ah[i], bh[j], acc[i][j], 0, 0, 0);
        acc[i][j] = __builtin_amdgcn_mfma_f32_16x16x32_bf16(al[i], bh[j], acc[i][j], 0, 0, 0);
      }
    __syncthreads();
  }

#pragma unroll
  for (int j = 0; j < 4; ++j) {
    int gc = n0 + wc + j * 16 + lrow;
    float bv = bias[gc];
#pragma unroll
    for (int i = 0; i < 4; ++i) {
#pragma unroll
      for (int rr = 0; rr < 4; ++rr) {
        int gr = m0 + wr + i * 16 + quad * 4 + rr;
        if (gr < M) {
          float v = fmaxf(acc[i][j][rr] + bv, 0.f);
          O1p[(size_t)gr * 256 + gc] = packhl(v);
        }
      }
    }
  }
}

// ---- final 256->1 dot (Z2 in bf16) ----
__global__ void k_finaldot(const unsigned short* __restrict__ Z2b, const float* __restrict__ wp3,
                           const float* __restrict__ bp3, void* __restrict__ out,
                           int base, int Pc, const int* __restrict__ flagp) {
  int wid = threadIdx.x >> 6, lane = threadIdx.x & 63;
  int p = blockIdx.x * 4 + wid;
  if (p >= Pc) return;
  uint2 zv = *(const uint2*)&Z2b[(size_t)p * 256 + lane * 4];
  float z0 = bf2f((unsigned short)zv.x), z1 = bf2f((unsigned short)(zv.x >> 16));
  float z2 = bf2f((unsigned short)zv.y), z3 = bf2f((unsigned short)(zv.y >> 16));
  float s = z0 * wp3[lane * 4 + 0] + z1 * wp3[lane * 4 + 1] +
            z2 * wp3[lane * 4 + 2] + z3 * wp3[lane * 4 + 3];
#pragma unroll
  for (int o = 32; o >= 1; o >>= 1) s += __shfl_xor(s, o, 64);
  if (lane == 0) {
    float r = s + bp3[0];
    if (*flagp) ((float*)out)[base + p] = r;
    else        ((unsigned short*)out)[base + p] = f2bf(r);
  }
}

extern "C" void kernel_launch(void* const* d_in, const int* in_sizes, int n_in,
                              void* d_out, int out_size, void* d_ws, size_t ws_size,
                              hipStream_t stream) {
  const int N = 50000, E = 800000, P = 100000, DIN = 128, DH = 256;
  const void* x = d_in[0];
  const int* esrc = (const int*)d_in[1];
  const int* edst = (const int*)d_in[2];
  const int* psrc = (const int*)d_in[3];
  const int* pdst = (const int*)d_in[4];
  const int* nsrc = (const int*)d_in[5];
  const int* ndst = (const int*)d_in[6];
  const void* Ws0 = d_in[7];  const void* Wn0 = d_in[8];  const void* b0 = d_in[9];
  const void* Ws1 = d_in[10]; const void* Wn1 = d_in[11]; const void* b1 = d_in[12];
  const void* Ws2 = d_in[13]; const void* Wn2 = d_in[14]; const void* b2 = d_in[15];
  const void* Wp1 = d_in[16]; const void* bp1 = d_in[17];
  const void* Wp2 = d_in[18]; const void* bp2 = d_in[19];
  const void* Wp3 = d_in[20]; const void* bp3 = d_in[21];
  (void)in_sizes; (void)n_in; (void)out_size; (void)ws_size;

  // ---- workspace: three regions (u32 [N,256] capacity each) ----
  const size_t NH = (size_t)N * DH;               // 12,800,000
  unsigned int* R_H = (unsigned int*)d_ws;        // H packed / Xp(L0)
  unsigned int* R_Y = R_H + NH;                   // Y packed (layers) / Z2 bf16 (pred)
  unsigned int* R_Z = R_Y + NH;                   // Zh bf16 (layers) / Z1 packed (pred)
  unsigned short* Zh = (unsigned short*)R_Z;
  unsigned short* Z2b = (unsigned short*)R_Y;
  unsigned short* W16 = (unsigned short*)(R_Z + NH);
  unsigned short* ws0h = W16;                     // K=128: 32768 each
  unsigned short* wn0h = ws0h + 32768;
  unsigned short* ws1h = wn0h + 32768;            // K=256: 65536 each
  unsigned short* wn1h = ws1h + 65536;
  unsigned short* ws2h = wn1h + 65536;
  unsigned short* wn2h = ws2h + 65536;
  unsigned short* wp1h = wn2h + 65536;
  unsigned short* wp2h = wp1h + 65536;
  float* FB = (float*)(wp2h + 65536);
  float* b0f  = FB;
  float* b1f  = b0f + 256;
  float* b2f  = b1f + 256;
  float* bp1f = b2f + 256;
  float* bp2f = bp1f + 256;
  float* wp3f = bp2f + 256;
  float* bp3f = wp3f + 256;
  int* deg   = (int*)(bp3f + 4);
  int* offs  = deg + N;
  int* cur   = offs + (N + 1);
  int* bsums = cur + N;
  int* csr   = bsums + 256;
  int* flagp = csr + E;
  // total ~158 MB

  unsigned int* Xp = R_H;

  // ---- dtype detection ----
  k_detect<<<1, 256, 0, stream>>>((const unsigned short*)x, 8192, flagp);

  // ---- weight hi-transpose + small cvts ----
  k_wh<<<CDIV(DIN * DH, 256), 256, 0, stream>>>(Ws0, ws0h, DIN, flagp);
  k_wh<<<CDIV(DIN * DH, 256), 256, 0, stream>>>(Wn0, wn0h, DIN, flagp);
  k_wh<<<CDIV(DH * DH, 256), 256, 0, stream>>>(Ws1, ws1h, DH, flagp);
  k_wh<<<CDIV(DH * DH, 256), 256, 0, stream>>>(Wn1, wn1h, DH, flagp);
  k_wh<<<CDIV(DH * DH, 256), 256, 0, stream>>>(Ws2, ws2h, DH, flagp);
  k_wh<<<CDIV(DH * DH, 256), 256, 0, stream>>>(Wn2, wn2h, DH, flagp);
  k_wh<<<CDIV(DH * DH, 256), 256, 0, stream>>>(Wp1, wp1h, DH, flagp);
  k_wh<<<CDIV(DH * DH, 256), 256, 0, stream>>>(Wp2, wp2h, DH, flagp);
  k_cvt7<<<7, 256, 0, stream>>>(b0, b1, b2, bp1, bp2, Wp3, bp3,
                                b0f, b1f, b2f, bp1f, bp2f, wp3f, bp3f, flagp);

  // ---- CSR build (deterministic: wave-bitonic sorted adjacency) ----
  int nb = CDIV(N, 256);
  k_zero_i32<<<nb, 256, 0, stream>>>(deg, N);
  k_deg<<<CDIV(E, 256), 256, 0, stream>>>(edst, deg, E);
  k_scan1<<<nb, 256, 0, stream>>>(deg, offs, bsums, N);
  k_scan2<<<1, 256, 0, stream>>>(bsums, nb);
  k_scan3<<<nb, 256, 0, stream>>>(offs, bsums, N, E);
  k_copy_i32<<<nb, 256, 0, stream>>>(offs, cur, N);
  k_fill<<<CDIV(E, 256), 256, 0, stream>>>(edst, esrc, cur, csr, E);
  k_sortw<<<CDIV(N, 4), 256, 0, stream>>>(offs, csr, N);

  const int MT = CDIV(N, 128);          // 391

  // ---- Layer 0: Y=x@Ws0 (packed), Zh=x@Wn0 (bf16); H = relu(Y + agg(Zh) + b0) ----
  k_splitpack<<<CDIV(N * DIN, 256), 256, 0, stream>>>(x, Xp, N * DIN, flagp);
  gemm2<<<MT * 4, 256, 0, stream>>>(Xp, DIN, ws0h, wn0h, N, 4, 0, (float*)0,
                                    R_Y, (unsigned short*)0, Zh);
  k_aggfuse<<<N / 4, 256, 0, stream>>>(R_Y, Zh, offs, csr, b0f, 1, R_H);

  // ---- Layer 1 ----
  gemm2<<<MT * 4, 256, 0, stream>>>(R_H, DH, ws1h, wn1h, N, 4, 0, (float*)0,
                                    R_Y, (unsigned short*)0, Zh);
  k_aggfuse<<<N / 4, 256, 0, stream>>>(R_Y, Zh, offs, csr, b1f, 1, R_H);

  // ---- Layer 2 (no relu) ----
  gemm2<<<MT * 4, 256, 0, stream>>>(R_H, DH, ws2h, wn2h, N, 4, 0, (float*)0,
                                    R_Y, (unsigned short*)0, Zh);
  k_aggfuse<<<N / 4, 256, 0, stream>>>(R_Y, Zh, offs, csr, b2f, 0, R_H);

  // ---- Predictor: 4 chunks of 50000 pairs, edge-gather fused into GEMM-1 ----
  const int PC = 50000;
  const int G_P = CDIV(PC, 128) * 2;
  for (int c = 0; c < 4; ++c) {
    int base = c * PC;
    // Z1 = relu((H[s]*H[d])@Wp1 + bp1): H -> R_Z packed
    gemm_pred1<<<G_P, 256, 0, stream>>>(R_H, psrc, pdst, nsrc, ndst, base, P,
                                        wp1h, bp1f, PC, R_Z);
    // Z2 = relu(Z1@Wp2 + bp2): R_Z -> Z2b (bf16 in R_Y)
    gemm2<<<G_P, 256, 0, stream>>>(R_Z, DH, wp2h, (unsigned short*)0, PC, 2, 1, bp2f,
                                   (unsigned int*)0, Z2b, (unsigned short*)0);
    k_finaldot<<<CDIV(PC, 4), 256, 0, stream>>>(Z2b, wp3f, bp3f, d_out, base, PC, flagp);
  }
}

// Round 11
// 762.692 us; speedup vs baseline: 1.9950x; 1.4793x over previous
//
#include <hip/hip_runtime.h>
#include <hip/hip_bf16.h>

#define CDIV(a, b) (((a) + (b) - 1) / (b))

typedef __attribute__((ext_vector_type(8))) __bf16 bf16x8;
typedef __attribute__((ext_vector_type(4))) float f32x4;

__device__ __forceinline__ float bf2f(unsigned short u) {
  union { unsigned int i; float f; } c; c.i = ((unsigned int)u) << 16; return c.f;
}
__device__ __forceinline__ unsigned short f2bf(float f) {
  union { float f; unsigned int i; } c; c.f = f;
  unsigned int r = c.i + 0x7fffu + ((c.i >> 16) & 1u);
  return (unsigned short)(r >> 16);
}
// packed hi/lo (u32 = hi | lo<<16) -- used only for the Y self-term
__device__ __forceinline__ float dec1(unsigned int u) {
  union { unsigned int i; float f; } a, b;
  a.i = u << 16; b.i = u & 0xffff0000u;
  return a.f + b.f;
}
__device__ __forceinline__ unsigned int packhl(float v) {
  unsigned short h = f2bf(v);
  unsigned short l = f2bf(v - bf2f(h));
  return (unsigned int)h | ((unsigned int)l << 16);
}

// ---- dtype detector: flag=1 if fp32 storage, 0 if bf16 storage ----
__global__ void k_detect(const unsigned short* __restrict__ xq, int nsamp, int* __restrict__ flagp) {
  __shared__ float sm[256];
  int t = threadIdx.x;
  float mx = 0.f;
  for (int i = t; i < nsamp; i += 256) {
    float v = bf2f(xq[i]);
    if (!(v == v)) v = 1e30f;
    mx = fmaxf(mx, fabsf(v));
  }
  sm[t] = mx; __syncthreads();
  for (int o = 128; o > 0; o >>= 1) {
    if (t < o) sm[t] = fmaxf(sm[t], sm[t + o]);
    __syncthreads();
  }
  if (t == 0) *flagp = (sm[0] > 1e6f) ? 1 : 0;
}

// ---- 7 small fp32 conversions in one dispatch ----
__global__ void k_cvt7(const void* p0, const void* p1, const void* p2, const void* p3,
                       const void* p4, const void* p5, const void* p6,
                       float* d0, float* d1, float* d2, float* d3,
                       float* d4, float* d5, float* d6, const int* __restrict__ flagp) {
  int b = blockIdx.x, t = threadIdx.x;
  const void* s = 0; float* d = 0; int n = 256;
  switch (b) {
    case 0: s = p0; d = d0; break;
    case 1: s = p1; d = d1; break;
    case 2: s = p2; d = d2; break;
    case 3: s = p3; d = d3; break;
    case 4: s = p4; d = d4; break;
    case 5: s = p5; d = d5; break;
    default: s = p6; d = d6; n = 1; break;
  }
  if (t < n) d[t] = (*flagp) ? ((const float*)s)[t] : bf2f(((const unsigned short*)s)[t]);
}

// ---- weight: W[K,256] -> transposed bf16 Bt[256,K] ----
__global__ void k_wh(const void* __restrict__ W, unsigned short* __restrict__ Bth,
                     int K, const int* __restrict__ flagp) {
  int i = blockIdx.x * 256 + threadIdx.x;
  if (i >= K * 256) return;
  int k = i >> 8, n = i & 255;
  float v = (*flagp) ? ((const float*)W)[i] : bf2f(((const unsigned short*)W)[i]);
  Bth[(size_t)n * K + k] = f2bf(v);
}

// ---- x -> bf16 plane ----
__global__ void k_xbf16(const void* __restrict__ x, unsigned short* __restrict__ Xb, int n,
                        const int* __restrict__ flagp) {
  int i = blockIdx.x * 256 + threadIdx.x;
  if (i >= n) return;
  float v = (*flagp) ? ((const float*)x)[i] : bf2f(((const unsigned short*)x)[i]);
  Xb[i] = f2bf(v);
}

__global__ void k_zero_i32(int* p, int n) {
  int i = blockIdx.x * 256 + threadIdx.x;
  if (i < n) p[i] = 0;
}
__global__ void k_zero_f32(float* p, int n) {
  int i = blockIdx.x * 256 + threadIdx.x;
  if (i < n) p[i] = 0.f;
}

// ---------------- CSR build ----------------
__global__ void k_deg(const int* __restrict__ dst, int* __restrict__ deg, int E) {
  int e = blockIdx.x * 256 + threadIdx.x;
  if (e < E) atomicAdd(&deg[dst[e]], 1);
}
__global__ void k_scan1(const int* __restrict__ in, int* __restrict__ out, int* __restrict__ bsums, int n) {
  __shared__ int sh[256];
  int t = threadIdx.x, i = blockIdx.x * 256 + t;
  int v = (i < n) ? in[i] : 0;
  sh[t] = v; __syncthreads();
  for (int o = 1; o < 256; o <<= 1) {
    int add = (t >= o) ? sh[t - o] : 0;
    __syncthreads();
    sh[t] += add;
    __syncthreads();
  }
  if (i < n) out[i] = sh[t] - v;
  if (t == 255) bsums[blockIdx.x] = sh[255];
}
__global__ void k_scan2(int* bsums, int nb) {
  __shared__ int sh[256];
  int t = threadIdx.x;
  int v = (t < nb) ? bsums[t] : 0;
  sh[t] = v; __syncthreads();
  for (int o = 1; o < 256; o <<= 1) {
    int add = (t >= o) ? sh[t - o] : 0;
    __syncthreads();
    sh[t] += add;
    __syncthreads();
  }
  if (t < nb) bsums[t] = sh[t] - v;
}
__global__ void k_scan3(int* offs, const int* bsums, int n, int etot) {
  int i = blockIdx.x * 256 + threadIdx.x;
  if (i < n) offs[i] += bsums[blockIdx.x];
  if (i == 0) offs[n] = etot;
}
__global__ void k_copy_i32(const int* __restrict__ a, int* __restrict__ b, int n) {
  int i = blockIdx.x * 256 + threadIdx.x;
  if (i < n) b[i] = a[i];
}
__global__ void k_fill(const int* __restrict__ dst, const int* __restrict__ src,
                       int* __restrict__ cursor, int* __restrict__ csr_src, int E) {
  int e = blockIdx.x * 256 + threadIdx.x;
  if (e >= E) return;
  int pos = atomicAdd(&cursor[dst[e]], 1);
  csr_src[pos] = src[e];
}
// ---- wave-parallel bitonic sort per node (deterministic adjacency order) ----
__global__ void k_sortw(const int* __restrict__ offs, int* __restrict__ csr, int n) {
  int w = threadIdx.x >> 6, lane = threadIdx.x & 63;
  int v = blockIdx.x * 4 + w;
  if (v >= n) return;
  int s = offs[v], e = offs[v + 1];
  int deg = e - s;
  if (deg <= 1) return;
  if (deg > 64) {
    if (lane == 0) {
      for (int i = s + 1; i < e; ++i) {
        int key = csr[i], j = i - 1;
        while (j >= s && csr[j] > key) { csr[j + 1] = csr[j]; --j; }
        csr[j + 1] = key;
      }
    }
    return;
  }
  int val = (lane < deg) ? csr[s + lane] : 0x7fffffff;
#pragma unroll
  for (int k = 2; k <= 64; k <<= 1) {
    bool dir = (lane & k) == 0;
#pragma unroll
    for (int j = k >> 1; j > 0; j >>= 1) {
      int p = __shfl_xor(val, j, 64);
      bool lower = (lane & j) == 0;
      val = (lower == dir) ? min(val, p) : max(val, p);
    }
  }
  if (lane < deg) csr[s + lane] = val;
}

// ---- fused agg epilogue: H[v] = act(Y[v] + mean_u Z[u] + b); H out = bf16 plane ----
__global__ void k_aggfuse(const unsigned int* __restrict__ Yp, const unsigned short* __restrict__ Zh,
                          const int* __restrict__ offs, const int* __restrict__ csr,
                          const float* __restrict__ bias, int relu,
                          unsigned short* __restrict__ Hb) {
  int w = threadIdx.x >> 6, lane = threadIdx.x & 63;
  int v = blockIdx.x * 4 + w;
  int c4 = lane * 4;
  uint4 yq = *(const uint4*)&Yp[(size_t)v * 256 + c4];
  int s = offs[v], e = offs[v + 1];
  float a0 = 0.f, a1 = 0.f, a2 = 0.f, a3 = 0.f;
  int i = s;
  for (; i + 2 <= e; i += 2) {
    uint2 z0 = *(const uint2*)&Zh[(size_t)csr[i] * 256 + c4];
    uint2 z1 = *(const uint2*)&Zh[(size_t)csr[i + 1] * 256 + c4];
    a0 += bf2f((unsigned short)z0.x) + bf2f((unsigned short)z1.x);
    a1 += bf2f((unsigned short)(z0.x >> 16)) + bf2f((unsigned short)(z1.x >> 16));
    a2 += bf2f((unsigned short)z0.y) + bf2f((unsigned short)z1.y);
    a3 += bf2f((unsigned short)(z0.y >> 16)) + bf2f((unsigned short)(z1.y >> 16));
  }
  if (i < e) {
    uint2 z0 = *(const uint2*)&Zh[(size_t)csr[i] * 256 + c4];
    a0 += bf2f((unsigned short)z0.x);
    a1 += bf2f((unsigned short)(z0.x >> 16));
    a2 += bf2f((unsigned short)z0.y);
    a3 += bf2f((unsigned short)(z0.y >> 16));
  }
  float inv = 1.f / fmaxf((float)(e - s), 1.f);
  float4 bv = *(const float4*)&bias[c4];
  float r0 = dec1(yq.x) + a0 * inv + bv.x;
  float r1 = dec1(yq.y) + a1 * inv + bv.y;
  float r2 = dec1(yq.z) + a2 * inv + bv.z;
  float r3 = dec1(yq.w) + a3 * inv + bv.w;
  if (relu) {
    r0 = fmaxf(r0, 0.f); r1 = fmaxf(r1, 0.f);
    r2 = fmaxf(r2, 0.f); r3 = fmaxf(r3, 0.f);
  }
  uint2 o;
  o.x = (unsigned int)f2bf(r0) | ((unsigned int)f2bf(r1) << 16);
  o.y = (unsigned int)f2bf(r2) | ((unsigned int)f2bf(r3) << 16);
  *(uint2*)&Hb[(size_t)v * 256 + c4] = o;
}

// ---- layer MFMA GEMM: A bf16 plane, dual B; Y packed (nt<2) / Zh bf16 (nt>=2) ----
// grid.x = CDIV(M,128)*4, block 256.
__global__ __launch_bounds__(256) void gemm2(
    const unsigned short* __restrict__ Ab, int K,
    const unsigned short* __restrict__ B1h, const unsigned short* __restrict__ B2h,
    int M, unsigned int* __restrict__ O1p, unsigned short* __restrict__ O2b) {
  __shared__ unsigned short sAh[128 * 40], sBh[128 * 40];
  int t = threadIdx.x;
  int mt = blockIdx.x >> 2, nt = blockIdx.x & 3;
  int m0 = mt * 128;
  const unsigned short* Bh = (nt < 2) ? B1h : B2h;
  int n0 = (nt & 1) * 128;
  int wid = t >> 6, lane = t & 63;
  int wr = (wid >> 1) * 64, wc = (wid & 1) * 64;
  int quad = lane >> 4, lrow = lane & 15;

  f32x4 acc[4][4];
  const f32x4 z4 = {0.f, 0.f, 0.f, 0.f};
#pragma unroll
  for (int i = 0; i < 4; ++i)
#pragma unroll
    for (int j = 0; j < 4; ++j) acc[i][j] = z4;

  int sr = t >> 2;
  int c8 = (t & 3) * 8;

  for (int k0 = 0; k0 < K; k0 += 32) {
#pragma unroll
    for (int rep = 0; rep < 2; ++rep) {
      int r = sr + rep * 64;
      int arow = m0 + r; if (arow >= M) arow = M - 1;
      *(uint4*)&sAh[r * 40 + c8] = *(const uint4*)&Ab[(size_t)arow * K + k0 + c8];
      *(uint4*)&sBh[r * 40 + c8] = *(const uint4*)&Bh[(size_t)(n0 + r) * K + k0 + c8];
    }
    __syncthreads();
    bf16x8 ah[4], bh[4];
#pragma unroll
    for (int i = 0; i < 4; ++i) {
      ah[i] = *(const bf16x8*)&sAh[(wr + i * 16 + lrow) * 40 + quad * 8];
      bh[i] = *(const bf16x8*)&sBh[(wc + i * 16 + lrow) * 40 + quad * 8];
    }
#pragma unroll
    for (int i = 0; i < 4; ++i)
#pragma unroll
      for (int j = 0; j < 4; ++j)
        acc[i][j] = __builtin_amdgcn_mfma_f32_16x16x32_bf16(ah[i], bh[j], acc[i][j], 0, 0, 0);
    __syncthreads();
  }

#pragma unroll
  for (int j = 0; j < 4; ++j) {
    int gc = n0 + wc + j * 16 + lrow;
#pragma unroll
    for (int i = 0; i < 4; ++i) {
#pragma unroll
      for (int rr = 0; rr < 4; ++rr) {
        int gr = m0 + wr + i * 16 + quad * 4 + rr;
        if (gr < M) {
          float v = acc[i][j][rr];
          size_t idx = (size_t)gr * 256 + gc;
          if (nt < 2) O1p[idx] = packhl(v);
          else        O2b[idx] = f2bf(v);
        }
      }
    }
  }
}

// ---- predictor GEMM-1, fused edge gather: Z1 = relu((H[s]*H[d])@Wp1^T + b) ----
// H is bf16 plane. Output Z1 bf16 plane. grid.x = CDIV(M,128)*2, block 256.
__global__ __launch_bounds__(256) void gemm_pred1(
    const unsigned short* __restrict__ Hb,
    const int* __restrict__ ps, const int* __restrict__ pd,
    const int* __restrict__ ns, const int* __restrict__ nd,
    int nPos, const unsigned short* __restrict__ Bh,
    const float* __restrict__ bias, int M, unsigned short* __restrict__ O1b) {
  __shared__ unsigned short sAh[128 * 40], sBh[128 * 40];
  int t = threadIdx.x;
  int mt = blockIdx.x >> 1, nt = blockIdx.x & 1;
  int m0 = mt * 128;
  int n0 = nt * 128;
  int wid = t >> 6, lane = t & 63;
  int wr = (wid >> 1) * 64, wc = (wid & 1) * 64;
  int quad = lane >> 4, lrow = lane & 15;

  f32x4 acc[4][4];
  const f32x4 z4 = {0.f, 0.f, 0.f, 0.f};
#pragma unroll
  for (int i = 0; i < 4; ++i)
#pragma unroll
    for (int j = 0; j < 4; ++j) acc[i][j] = z4;

  int sr = t >> 2;
  int c8 = (t & 3) * 8;

  const unsigned short* Hs[2];
  const unsigned short* Hd[2];
#pragma unroll
  for (int rep = 0; rep < 2; ++rep) {
    int arow = m0 + sr + rep * 64; if (arow >= M) arow = M - 1;
    int s, d;
    if (arow < nPos) { s = ps[arow]; d = pd[arow]; }
    else             { s = ns[arow - nPos]; d = nd[arow - nPos]; }
    Hs[rep] = &Hb[(size_t)s * 256];
    Hd[rep] = &Hb[(size_t)d * 256];
  }

  for (int k0 = 0; k0 < 256; k0 += 32) {
#pragma unroll
    for (int rep = 0; rep < 2; ++rep) {
      int r = sr + rep * 64;
      uint4 hs = *(const uint4*)(Hs[rep] + k0 + c8);   // 8 bf16
      uint4 hd = *(const uint4*)(Hd[rep] + k0 + c8);
      uint4 o;
      unsigned int e0, e1;
      e0 = f2bf(bf2f((unsigned short)hs.x) * bf2f((unsigned short)hd.x));
      e1 = f2bf(bf2f((unsigned short)(hs.x >> 16)) * bf2f((unsigned short)(hd.x >> 16)));
      o.x = e0 | (e1 << 16);
      e0 = f2bf(bf2f((unsigned short)hs.y) * bf2f((unsigned short)hd.y));
      e1 = f2bf(bf2f((unsigned short)(hs.y >> 16)) * bf2f((unsigned short)(hd.y >> 16)));
      o.y = e0 | (e1 << 16);
      e0 = f2bf(bf2f((unsigned short)hs.z) * bf2f((unsigned short)hd.z));
      e1 = f2bf(bf2f((unsigned short)(hs.z >> 16)) * bf2f((unsigned short)(hd.z >> 16)));
      o.z = e0 | (e1 << 16);
      e0 = f2bf(bf2f((unsigned short)hs.w) * bf2f((unsigned short)hd.w));
      e1 = f2bf(bf2f((unsigned short)(hs.w >> 16)) * bf2f((unsigned short)(hd.w >> 16)));
      o.w = e0 | (e1 << 16);
      *(uint4*)&sAh[r * 40 + c8] = o;
      *(uint4*)&sBh[r * 40 + c8] = *(const uint4*)&Bh[(size_t)(n0 + r) * 256 + k0 + c8];
    }
    __syncthreads();
    bf16x8 ah[4], bh[4];
#pragma unroll
    for (int i = 0; i < 4; ++i) {
      ah[i] = *(const bf16x8*)&sAh[(wr + i * 16 + lrow) * 40 + quad * 8];
      bh[i] = *(const bf16x8*)&sBh[(wc + i * 16 + lrow) * 40 + quad * 8];
    }
#pragma unroll
    for (int i = 0; i < 4; ++i)
#pragma unroll
      for (int j = 0; j < 4; ++j)
        acc[i][j] = __builtin_amdgcn_mfma_f32_16x16x32_bf16(ah[i], bh[j], acc[i][j], 0, 0, 0);
    __syncthreads();
  }

#pragma unroll
  for (int j = 0; j < 4; ++j) {
    int gc = n0 + wc + j * 16 + lrow;
    float bv = bias[gc];
#pragma unroll
    for (int i = 0; i < 4; ++i) {
#pragma unroll
      for (int rr = 0; rr < 4; ++rr) {
        int gr = m0 + wr + i * 16 + quad * 4 + rr;
        if (gr < M) {
          float v = fmaxf(acc[i][j][rr] + bv, 0.f);
          O1b[(size_t)gr * 256 + gc] = f2bf(v);
        }
      }
    }
  }
}

// ---- predictor GEMM-2 with fused final dot: Pout[p] += relu(Z1@Wp2+b)[p,:].wp3 ----
// A = Z1 bf16 plane. Two blocks per row tile (nt=0,1) -> exactly 2 atomicAdds/row.
__global__ __launch_bounds__(256) void gemm_dot(
    const unsigned short* __restrict__ Ab,
    const unsigned short* __restrict__ Bh, const float* __restrict__ bias,
    const float* __restrict__ wp3, int M, float* __restrict__ Pout) {
  __shared__ unsigned short sAh[128 * 40], sBh[128 * 40];
  __shared__ float part[128][33];
  int t = threadIdx.x;
  int mt = blockIdx.x >> 1, nt = blockIdx.x & 1;
  int m0 = mt * 128;
  int n0 = nt * 128;
  int wid = t >> 6, lane = t & 63;
  int wr = (wid >> 1) * 64, wc = (wid & 1) * 64;
  int quad = lane >> 4, lrow = lane & 15;

  f32x4 acc[4][4];
  const f32x4 z4 = {0.f, 0.f, 0.f, 0.f};
#pragma unroll
  for (int i = 0; i < 4; ++i)
#pragma unroll
    for (int j = 0; j < 4; ++j) acc[i][j] = z4;

  int sr = t >> 2;
  int c8 = (t & 3) * 8;

  for (int k0 = 0; k0 < 256; k0 += 32) {
#pragma unroll
    for (int rep = 0; rep < 2; ++rep) {
      int r = sr + rep * 64;
      int arow = m0 + r; if (arow >= M) arow = M - 1;
      *(uint4*)&sAh[r * 40 + c8] = *(const uint4*)&Ab[(size_t)arow * 256 + k0 + c8];
      *(uint4*)&sBh[r * 40 + c8] = *(const uint4*)&Bh[(size_t)(n0 + r) * 256 + k0 + c8];
    }
    __syncthreads();
    bf16x8 ah[4], bh[4];
#pragma unroll
    for (int i = 0; i < 4; ++i) {
      ah[i] = *(const bf16x8*)&sAh[(wr + i * 16 + lrow) * 40 + quad * 8];
      bh[i] = *(const bf16x8*)&sBh[(wc + i * 16 + lrow) * 40 + quad * 8];
    }
#pragma unroll
    for (int i = 0; i < 4; ++i)
#pragma unroll
      for (int j = 0; j < 4; ++j)
        acc[i][j] = __builtin_amdgcn_mfma_f32_16x16x32_bf16(ah[i], bh[j], acc[i][j], 0, 0, 0);
    __syncthreads();
  }

  // per-lane partial dot over its 4 cols; deposit at unique (row, cid) slot
  int cid = (wid & 1) * 16 + lrow;
#pragma unroll
  for (int i = 0; i < 4; ++i) {
#pragma unroll
    for (int rr = 0; rr < 4; ++rr) {
      int rloc = wr + i * 16 + quad * 4 + rr;
      float s = 0.f;
#pragma unroll
      for (int j = 0; j < 4; ++j) {
        int gc = n0 + wc + j * 16 + lrow;
        float v = fmaxf(acc[i][j][rr] + bias[gc], 0.f);
        s += v * wp3[gc];
      }
      part[rloc][cid] = s;
    }
  }
  __syncthreads();
  if (t < 128) {
    int gr = m0 + t;
    if (gr < M) {
      float s = 0.f;
#pragma unroll
      for (int c = 0; c < 32; ++c) s += part[t][c];
      atomicAdd(&Pout[gr], s);
    }
  }
}

// ---- finish: out[p] = Pout[p] + bp3 (dual-dtype store) ----
__global__ void k_finish(const float* __restrict__ Pout, const float* __restrict__ bp3,
                         void* __restrict__ out, int n, const int* __restrict__ flagp) {
  int p = blockIdx.x * 256 + threadIdx.x;
  if (p >= n) return;
  float r = Pout[p] + bp3[0];
  if (*flagp) ((float*)out)[p] = r;
  else        ((unsigned short*)out)[p] = f2bf(r);
}

extern "C" void kernel_launch(void* const* d_in, const int* in_sizes, int n_in,
                              void* d_out, int out_size, void* d_ws, size_t ws_size,
                              hipStream_t stream) {
  const int N = 50000, E = 800000, P = 100000, DIN = 128, DH = 256;
  const int M2 = 2 * P;                 // 200000 predictor rows
  const void* x = d_in[0];
  const int* esrc = (const int*)d_in[1];
  const int* edst = (const int*)d_in[2];
  const int* psrc = (const int*)d_in[3];
  const int* pdst = (const int*)d_in[4];
  const int* nsrc = (const int*)d_in[5];
  const int* ndst = (const int*)d_in[6];
  const void* Ws0 = d_in[7];  const void* Wn0 = d_in[8];  const void* b0 = d_in[9];
  const void* Ws1 = d_in[10]; const void* Wn1 = d_in[11]; const void* b1 = d_in[12];
  const void* Ws2 = d_in[13]; const void* Wn2 = d_in[14]; const void* b2 = d_in[15];
  const void* Wp1 = d_in[16]; const void* bp1 = d_in[17];
  const void* Wp2 = d_in[18]; const void* bp2 = d_in[19];
  const void* Wp3 = d_in[20]; const void* bp3 = d_in[21];
  (void)in_sizes; (void)n_in; (void)out_size; (void)ws_size;

  // ---- workspace layout ----
  const size_t NH = (size_t)N * DH;               // 12.8M elems
  unsigned short* Hb = (unsigned short*)d_ws;     // [N,256] bf16 (also Xb for L0)
  unsigned short* Xb = Hb;                        // [N,128] bf16 (dead after L0 gemm)
  char* reg1 = (char*)d_ws + NH * 2;              // 102.4 MB region
  unsigned int* Yp = (unsigned int*)reg1;         // layers: [N,256] packed u32
  unsigned short* Zh = (unsigned short*)(reg1 + NH * 4);  // layers: [N,256] bf16
  unsigned short* Z1b = (unsigned short*)reg1;    // predictor: [200000,256] bf16
  float* Pout = (float*)(reg1 + (size_t)M2 * 256 * 2);    // [200000] fp32
  unsigned short* W16 = (unsigned short*)(Pout + M2);
  unsigned short* ws0h = W16;                     // K=128: 32768 each
  unsigned short* wn0h = ws0h + 32768;
  unsigned short* ws1h = wn0h + 32768;            // K=256: 65536 each
  unsigned short* wn1h = ws1h + 65536;
  unsigned short* ws2h = wn1h + 65536;
  unsigned short* wn2h = ws2h + 65536;
  unsigned short* wp1h = wn2h + 65536;
  unsigned short* wp2h = wp1h + 65536;
  float* FB = (float*)(wp2h + 65536);
  float* b0f  = FB;
  float* b1f  = b0f + 256;
  float* b2f  = b1f + 256;
  float* bp1f = b2f + 256;
  float* bp2f = bp1f + 256;
  float* wp3f = bp2f + 256;
  float* bp3f = wp3f + 256;
  int* deg   = (int*)(bp3f + 4);
  int* offs  = deg + N;
  int* cur   = offs + (N + 1);
  int* bsums = cur + N;
  int* csr   = bsums + 256;
  int* flagp = csr + E;
  // total ~134 MB

  // ---- dtype detection ----
  k_detect<<<1, 256, 0, stream>>>((const unsigned short*)x, 8192, flagp);

  // ---- weight transpose-to-bf16 + small cvts ----
  k_wh<<<CDIV(DIN * DH, 256), 256, 0, stream>>>(Ws0, ws0h, DIN, flagp);
  k_wh<<<CDIV(DIN * DH, 256), 256, 0, stream>>>(Wn0, wn0h, DIN, flagp);
  k_wh<<<CDIV(DH * DH, 256), 256, 0, stream>>>(Ws1, ws1h, DH, flagp);
  k_wh<<<CDIV(DH * DH, 256), 256, 0, stream>>>(Wn1, wn1h, DH, flagp);
  k_wh<<<CDIV(DH * DH, 256), 256, 0, stream>>>(Ws2, ws2h, DH, flagp);
  k_wh<<<CDIV(DH * DH, 256), 256, 0, stream>>>(Wn2, wn2h, DH, flagp);
  k_wh<<<CDIV(DH * DH, 256), 256, 0, stream>>>(Wp1, wp1h, DH, flagp);
  k_wh<<<CDIV(DH * DH, 256), 256, 0, stream>>>(Wp2, wp2h, DH, flagp);
  k_cvt7<<<7, 256, 0, stream>>>(b0, b1, b2, bp1, bp2, Wp3, bp3,
                                b0f, b1f, b2f, bp1f, bp2f, wp3f, bp3f, flagp);

  // ---- CSR build (deterministic) ----
  int nb = CDIV(N, 256);
  k_zero_i32<<<nb, 256, 0, stream>>>(deg, N);
  k_deg<<<CDIV(E, 256), 256, 0, stream>>>(edst, deg, E);
  k_scan1<<<nb, 256, 0, stream>>>(deg, offs, bsums, N);
  k_scan2<<<1, 256, 0, stream>>>(bsums, nb);
  k_scan3<<<nb, 256, 0, stream>>>(offs, bsums, N, E);
  k_copy_i32<<<nb, 256, 0, stream>>>(offs, cur, N);
  k_fill<<<CDIV(E, 256), 256, 0, stream>>>(edst, esrc, cur, csr, E);
  k_sortw<<<CDIV(N, 4), 256, 0, stream>>>(offs, csr, N);

  const int MT = CDIV(N, 128);          // 391

  // ---- Layer 0: Y=x@Ws0, Zh=x@Wn0; H = relu(Y + agg(Zh) + b0) ----
  k_xbf16<<<CDIV(N * DIN, 256), 256, 0, stream>>>(x, Xb, N * DIN, flagp);
  gemm2<<<MT * 4, 256, 0, stream>>>(Xb, DIN, ws0h, wn0h, N, Yp, Zh);
  k_aggfuse<<<N / 4, 256, 0, stream>>>(Yp, Zh, offs, csr, b0f, 1, Hb);

  // ---- Layer 1 ----
  gemm2<<<MT * 4, 256, 0, stream>>>(Hb, DH, ws1h, wn1h, N, Yp, Zh);
  k_aggfuse<<<N / 4, 256, 0, stream>>>(Yp, Zh, offs, csr, b1f, 1, Hb);

  // ---- Layer 2 (no relu) ----
  gemm2<<<MT * 4, 256, 0, stream>>>(Hb, DH, ws2h, wn2h, N, Yp, Zh);
  k_aggfuse<<<N / 4, 256, 0, stream>>>(Yp, Zh, offs, csr, b2f, 0, Hb);

  // ---- Predictor, single pass over all 200000 pairs ----
  const int G_P = CDIV(M2, 128) * 2;    // 3126 blocks
  // Z1 = relu((H[s]*H[d])@Wp1 + bp1) -> Z1b (overwrites Yp/Zh region)
  gemm_pred1<<<G_P, 256, 0, stream>>>(Hb, psrc, pdst, nsrc, ndst, P,
                                      wp1h, bp1f, M2, Z1b);
  // Pout = rowdot(relu(Z1@Wp2 + bp2), wp3)
  k_zero_f32<<<CDIV(M2, 256), 256, 0, stream>>>(Pout, M2);
  gemm_dot<<<G_P, 256, 0, stream>>>(Z1b, wp2h, bp2f, wp3f, M2, Pout);
  k_finish<<<CDIV(M2, 256), 256, 0, stream>>>(Pout, bp3f, d_out, M2, flagp);
}

// Round 12
// 754.068 us; speedup vs baseline: 2.0178x; 1.0114x over previous
//
#include <hip/hip_runtime.h>
#include <hip/hip_bf16.h>

#define CDIV(a, b) (((a) + (b) - 1) / (b))

typedef __attribute__((ext_vector_type(8))) __bf16 bf16x8;
typedef __attribute__((ext_vector_type(2))) __bf16 bf16x2;
typedef __attribute__((ext_vector_type(4))) float f32x4;

__device__ __forceinline__ float bf2f(unsigned short u) {
  union { unsigned int i; float f; } c; c.i = ((unsigned int)u) << 16; return c.f;
}
__device__ __forceinline__ unsigned short f2bf(float f) {
  union { float f; unsigned int i; } c; c.f = f;
  unsigned int r = c.i + 0x7fffu + ((c.i >> 16) & 1u);
  return (unsigned short)(r >> 16);
}
// two floats -> packed bf16x2 in one u32 (v_cvt_pk_bf16_f32)
__device__ __forceinline__ unsigned int cvt2(float a, float b) {
  bf16x2 v; v[0] = (__bf16)a; v[1] = (__bf16)b;
  union { bf16x2 v; unsigned int u; } c; c.v = v; return c.u;
}
__device__ __forceinline__ unsigned short cvt1(float a) {
  __bf16 b = (__bf16)a;
  union { __bf16 b; unsigned short u; } c; c.b = b; return c.u;
}
// packed hi/lo (u32 = hi | lo<<16) -- Y self-term only
__device__ __forceinline__ float dec1(unsigned int u) {
  union { unsigned int i; float f; } a, b;
  a.i = u << 16; b.i = u & 0xffff0000u;
  return a.f + b.f;
}
__device__ __forceinline__ unsigned int packhl(float v) {
  __bf16 h = (__bf16)v;
  float hf = (float)h;
  __bf16 l = (__bf16)(v - hf);
  bf16x2 p; p[0] = h; p[1] = l;
  union { bf16x2 v; unsigned int u; } c; c.v = p; return c.u;
}

// ---- dtype detector: flag=1 if fp32 storage, 0 if bf16 storage ----
__global__ void k_detect(const unsigned short* __restrict__ xq, int nsamp, int* __restrict__ flagp) {
  __shared__ float sm[256];
  int t = threadIdx.x;
  float mx = 0.f;
  for (int i = t; i < nsamp; i += 256) {
    float v = bf2f(xq[i]);
    if (!(v == v)) v = 1e30f;
    mx = fmaxf(mx, fabsf(v));
  }
  sm[t] = mx; __syncthreads();
  for (int o = 128; o > 0; o >>= 1) {
    if (t < o) sm[t] = fmaxf(sm[t], sm[t + o]);
    __syncthreads();
  }
  if (t == 0) *flagp = (sm[0] > 1e6f) ? 1 : 0;
}

// ---- 7 small fp32 conversions in one dispatch ----
__global__ void k_cvt7(const void* p0, const void* p1, const void* p2, const void* p3,
                       const void* p4, const void* p5, const void* p6,
                       float* d0, float* d1, float* d2, float* d3,
                       float* d4, float* d5, float* d6, const int* __restrict__ flagp) {
  int b = blockIdx.x, t = threadIdx.x;
  const void* s = 0; float* d = 0; int n = 256;
  switch (b) {
    case 0: s = p0; d = d0; break;
    case 1: s = p1; d = d1; break;
    case 2: s = p2; d = d2; break;
    case 3: s = p3; d = d3; break;
    case 4: s = p4; d = d4; break;
    case 5: s = p5; d = d5; break;
    default: s = p6; d = d6; n = 1; break;
  }
  if (t < n) d[t] = (*flagp) ? ((const float*)s)[t] : bf2f(((const unsigned short*)s)[t]);
}

// ---- weight: W[K,256] -> transposed bf16 Bt[256,K] ----
__global__ void k_wh(const void* __restrict__ W, unsigned short* __restrict__ Bth,
                     int K, const int* __restrict__ flagp) {
  int i = blockIdx.x * 256 + threadIdx.x;
  if (i >= K * 256) return;
  int k = i >> 8, n = i & 255;
  float v = (*flagp) ? ((const float*)W)[i] : bf2f(((const unsigned short*)W)[i]);
  Bth[(size_t)n * K + k] = f2bf(v);
}

// ---- x -> bf16 plane ----
__global__ void k_xbf16(const void* __restrict__ x, unsigned short* __restrict__ Xb, int n,
                        const int* __restrict__ flagp) {
  int i = blockIdx.x * 256 + threadIdx.x;
  if (i >= n) return;
  float v = (*flagp) ? ((const float*)x)[i] : bf2f(((const unsigned short*)x)[i]);
  Xb[i] = f2bf(v);
}

__global__ void k_zero_i32(int* p, int n) {
  int i = blockIdx.x * 256 + threadIdx.x;
  if (i < n) p[i] = 0;
}

// ---------------- CSR build ----------------
__global__ void k_deg(const int* __restrict__ dst, int* __restrict__ deg, int E) {
  int e = blockIdx.x * 256 + threadIdx.x;
  if (e < E) atomicAdd(&deg[dst[e]], 1);
}
__global__ void k_scan1(const int* __restrict__ in, int* __restrict__ out, int* __restrict__ bsums, int n) {
  __shared__ int sh[256];
  int t = threadIdx.x, i = blockIdx.x * 256 + t;
  int v = (i < n) ? in[i] : 0;
  sh[t] = v; __syncthreads();
  for (int o = 1; o < 256; o <<= 1) {
    int add = (t >= o) ? sh[t - o] : 0;
    __syncthreads();
    sh[t] += add;
    __syncthreads();
  }
  if (i < n) out[i] = sh[t] - v;
  if (t == 255) bsums[blockIdx.x] = sh[255];
}
__global__ void k_scan2(int* bsums, int nb) {
  __shared__ int sh[256];
  int t = threadIdx.x;
  int v = (t < nb) ? bsums[t] : 0;
  sh[t] = v; __syncthreads();
  for (int o = 1; o < 256; o <<= 1) {
    int add = (t >= o) ? sh[t - o] : 0;
    __syncthreads();
    sh[t] += add;
    __syncthreads();
  }
  if (t < nb) bsums[t] = sh[t] - v;
}
__global__ void k_scan3(int* offs, const int* bsums, int n, int etot) {
  int i = blockIdx.x * 256 + threadIdx.x;
  if (i < n) offs[i] += bsums[blockIdx.x];
  if (i == 0) offs[n] = etot;
}
__global__ void k_copy_i32(const int* __restrict__ a, int* __restrict__ b, int n) {
  int i = blockIdx.x * 256 + threadIdx.x;
  if (i < n) b[i] = a[i];
}
__global__ void k_fill(const int* __restrict__ dst, const int* __restrict__ src,
                       int* __restrict__ cursor, int* __restrict__ csr_src, int E) {
  int e = blockIdx.x * 256 + threadIdx.x;
  if (e >= E) return;
  int pos = atomicAdd(&cursor[dst[e]], 1);
  csr_src[pos] = src[e];
}
// ---- wave-parallel bitonic sort per node ----
__global__ void k_sortw(const int* __restrict__ offs, int* __restrict__ csr, int n) {
  int w = threadIdx.x >> 6, lane = threadIdx.x & 63;
  int v = blockIdx.x * 4 + w;
  if (v >= n) return;
  int s = offs[v], e = offs[v + 1];
  int deg = e - s;
  if (deg <= 1) return;
  if (deg > 64) {
    if (lane == 0) {
      for (int i = s + 1; i < e; ++i) {
        int key = csr[i], j = i - 1;
        while (j >= s && csr[j] > key) { csr[j + 1] = csr[j]; --j; }
        csr[j + 1] = key;
      }
    }
    return;
  }
  int val = (lane < deg) ? csr[s + lane] : 0x7fffffff;
#pragma unroll
  for (int k = 2; k <= 64; k <<= 1) {
    bool dir = (lane & k) == 0;
#pragma unroll
    for (int j = k >> 1; j > 0; j >>= 1) {
      int p = __shfl_xor(val, j, 64);
      bool lower = (lane & j) == 0;
      val = (lower == dir) ? min(val, p) : max(val, p);
    }
  }
  if (lane < deg) csr[s + lane] = val;
}

// ---- fused agg epilogue: H[v] = act(Y[v] + mean_u Z[u] + b); H out bf16 ----
__global__ void k_aggfuse(const unsigned int* __restrict__ Yp, const unsigned short* __restrict__ Zh,
                          const int* __restrict__ offs, const int* __restrict__ csr,
                          const float* __restrict__ bias, int relu,
                          unsigned short* __restrict__ Hb) {
  int w = threadIdx.x >> 6, lane = threadIdx.x & 63;
  int v = blockIdx.x * 4 + w;
  int c4 = lane * 4;
  uint4 yq = *(const uint4*)&Yp[(size_t)v * 256 + c4];
  int s = offs[v], e = offs[v + 1];
  float a0 = 0.f, a1 = 0.f, a2 = 0.f, a3 = 0.f;
  int i = s;
  for (; i + 2 <= e; i += 2) {
    uint2 z0 = *(const uint2*)&Zh[(size_t)csr[i] * 256 + c4];
    uint2 z1 = *(const uint2*)&Zh[(size_t)csr[i + 1] * 256 + c4];
    a0 += bf2f((unsigned short)z0.x) + bf2f((unsigned short)z1.x);
    a1 += bf2f((unsigned short)(z0.x >> 16)) + bf2f((unsigned short)(z1.x >> 16));
    a2 += bf2f((unsigned short)z0.y) + bf2f((unsigned short)z1.y);
    a3 += bf2f((unsigned short)(z0.y >> 16)) + bf2f((unsigned short)(z1.y >> 16));
  }
  if (i < e) {
    uint2 z0 = *(const uint2*)&Zh[(size_t)csr[i] * 256 + c4];
    a0 += bf2f((unsigned short)z0.x);
    a1 += bf2f((unsigned short)(z0.x >> 16));
    a2 += bf2f((unsigned short)z0.y);
    a3 += bf2f((unsigned short)(z0.y >> 16));
  }
  float inv = 1.f / fmaxf((float)(e - s), 1.f);
  float4 bv = *(const float4*)&bias[c4];
  float r0 = dec1(yq.x) + a0 * inv + bv.x;
  float r1 = dec1(yq.y) + a1 * inv + bv.y;
  float r2 = dec1(yq.z) + a2 * inv + bv.z;
  float r3 = dec1(yq.w) + a3 * inv + bv.w;
  if (relu) {
    r0 = fmaxf(r0, 0.f); r1 = fmaxf(r1, 0.f);
    r2 = fmaxf(r2, 0.f); r3 = fmaxf(r3, 0.f);
  }
  uint2 o;
  o.x = cvt2(r0, r1);
  o.y = cvt2(r2, r3);
  *(uint2*)&Hb[(size_t)v * 256 + c4] = o;
}

// ---- layer MFMA GEMM: A bf16 plane, dual B; Y packed (nt<2) / Zh bf16 (nt>=2) ----
__global__ __launch_bounds__(256) void gemm2(
    const unsigned short* __restrict__ Ab, int K,
    const unsigned short* __restrict__ B1h, const unsigned short* __restrict__ B2h,
    int M, unsigned int* __restrict__ O1p, unsigned short* __restrict__ O2b) {
  __shared__ unsigned short sAh[128 * 40], sBh[128 * 40];
  int t = threadIdx.x;
  int mt = blockIdx.x >> 2, nt = blockIdx.x & 3;
  int m0 = mt * 128;
  const unsigned short* Bh = (nt < 2) ? B1h : B2h;
  int n0 = (nt & 1) * 128;
  int wid = t >> 6, lane = t & 63;
  int wr = (wid >> 1) * 64, wc = (wid & 1) * 64;
  int quad = lane >> 4, lrow = lane & 15;

  f32x4 acc[4][4];
  const f32x4 z4 = {0.f, 0.f, 0.f, 0.f};
#pragma unroll
  for (int i = 0; i < 4; ++i)
#pragma unroll
    for (int j = 0; j < 4; ++j) acc[i][j] = z4;

  int sr = t >> 2;
  int c8 = (t & 3) * 8;

  for (int k0 = 0; k0 < K; k0 += 32) {
#pragma unroll
    for (int rep = 0; rep < 2; ++rep) {
      int r = sr + rep * 64;
      int arow = m0 + r; if (arow >= M) arow = M - 1;
      *(uint4*)&sAh[r * 40 + c8] = *(const uint4*)&Ab[(size_t)arow * K + k0 + c8];
      *(uint4*)&sBh[r * 40 + c8] = *(const uint4*)&Bh[(size_t)(n0 + r) * K + k0 + c8];
    }
    __syncthreads();
    bf16x8 ah[4], bh[4];
#pragma unroll
    for (int i = 0; i < 4; ++i) {
      ah[i] = *(const bf16x8*)&sAh[(wr + i * 16 + lrow) * 40 + quad * 8];
      bh[i] = *(const bf16x8*)&sBh[(wc + i * 16 + lrow) * 40 + quad * 8];
    }
#pragma unroll
    for (int i = 0; i < 4; ++i)
#pragma unroll
      for (int j = 0; j < 4; ++j)
        acc[i][j] = __builtin_amdgcn_mfma_f32_16x16x32_bf16(ah[i], bh[j], acc[i][j], 0, 0, 0);
    __syncthreads();
  }

#pragma unroll
  for (int j = 0; j < 4; ++j) {
    int gc = n0 + wc + j * 16 + lrow;
#pragma unroll
    for (int i = 0; i < 4; ++i) {
#pragma unroll
      for (int rr = 0; rr < 4; ++rr) {
        int gr = m0 + wr + i * 16 + quad * 4 + rr;
        if (gr < M) {
          float v = acc[i][j][rr];
          size_t idx = (size_t)gr * 256 + gc;
          if (nt < 2) O1p[idx] = packhl(v);
          else        O2b[idx] = cvt1(v);
        }
      }
    }
  }
}

// ---- predictor GEMM-1, fused edge gather: Z1 = relu((H[s]*H[d])@Wp1^T + b) ----
__global__ __launch_bounds__(256) void gemm_pred1(
    const unsigned short* __restrict__ Hb,
    const int* __restrict__ ps, const int* __restrict__ pd,
    const int* __restrict__ ns, const int* __restrict__ nd,
    int nPos, const unsigned short* __restrict__ Bh,
    const float* __restrict__ bias, int M, unsigned short* __restrict__ O1b) {
  __shared__ unsigned short sAh[128 * 40], sBh[128 * 40];
  int t = threadIdx.x;
  int mt = blockIdx.x >> 1, nt = blockIdx.x & 1;
  int m0 = mt * 128;
  int n0 = nt * 128;
  int wid = t >> 6, lane = t & 63;
  int wr = (wid >> 1) * 64, wc = (wid & 1) * 64;
  int quad = lane >> 4, lrow = lane & 15;

  f32x4 acc[4][4];
  const f32x4 z4 = {0.f, 0.f, 0.f, 0.f};
#pragma unroll
  for (int i = 0; i < 4; ++i)
#pragma unroll
    for (int j = 0; j < 4; ++j) acc[i][j] = z4;

  int sr = t >> 2;
  int c8 = (t & 3) * 8;

  const unsigned short* Hs[2];
  const unsigned short* Hd[2];
#pragma unroll
  for (int rep = 0; rep < 2; ++rep) {
    int arow = m0 + sr + rep * 64; if (arow >= M) arow = M - 1;
    int s, d;
    if (arow < nPos) { s = ps[arow]; d = pd[arow]; }
    else             { s = ns[arow - nPos]; d = nd[arow - nPos]; }
    Hs[rep] = &Hb[(size_t)s * 256];
    Hd[rep] = &Hb[(size_t)d * 256];
  }

  for (int k0 = 0; k0 < 256; k0 += 32) {
#pragma unroll
    for (int rep = 0; rep < 2; ++rep) {
      int r = sr + rep * 64;
      uint4 hs = *(const uint4*)(Hs[rep] + k0 + c8);   // 8 bf16
      uint4 hd = *(const uint4*)(Hd[rep] + k0 + c8);
      float e0 = bf2f((unsigned short)hs.x) * bf2f((unsigned short)hd.x);
      float e1 = bf2f((unsigned short)(hs.x >> 16)) * bf2f((unsigned short)(hd.x >> 16));
      float e2 = bf2f((unsigned short)hs.y) * bf2f((unsigned short)hd.y);
      float e3 = bf2f((unsigned short)(hs.y >> 16)) * bf2f((unsigned short)(hd.y >> 16));
      float e4 = bf2f((unsigned short)hs.z) * bf2f((unsigned short)hd.z);
      float e5 = bf2f((unsigned short)(hs.z >> 16)) * bf2f((unsigned short)(hd.z >> 16));
      float e6 = bf2f((unsigned short)hs.w) * bf2f((unsigned short)hd.w);
      float e7 = bf2f((unsigned short)(hs.w >> 16)) * bf2f((unsigned short)(hd.w >> 16));
      uint4 o;
      o.x = cvt2(e0, e1);
      o.y = cvt2(e2, e3);
      o.z = cvt2(e4, e5);
      o.w = cvt2(e6, e7);
      *(uint4*)&sAh[r * 40 + c8] = o;
      *(uint4*)&sBh[r * 40 + c8] = *(const uint4*)&Bh[(size_t)(n0 + r) * 256 + k0 + c8];
    }
    __syncthreads();
    bf16x8 ah[4], bh[4];
#pragma unroll
    for (int i = 0; i < 4; ++i) {
      ah[i] = *(const bf16x8*)&sAh[(wr + i * 16 + lrow) * 40 + quad * 8];
      bh[i] = *(const bf16x8*)&sBh[(wc + i * 16 + lrow) * 40 + quad * 8];
    }
#pragma unroll
    for (int i = 0; i < 4; ++i)
#pragma unroll
      for (int j = 0; j < 4; ++j)
        acc[i][j] = __builtin_amdgcn_mfma_f32_16x16x32_bf16(ah[i], bh[j], acc[i][j], 0, 0, 0);
    __syncthreads();
  }

#pragma unroll
  for (int j = 0; j < 4; ++j) {
    int gc = n0 + wc + j * 16 + lrow;
    float bv = bias[gc];
#pragma unroll
    for (int i = 0; i < 4; ++i) {
#pragma unroll
      for (int rr = 0; rr < 4; ++rr) {
        int gr = m0 + wr + i * 16 + quad * 4 + rr;
        if (gr < M) {
          float v = fmaxf(acc[i][j][rr] + bv, 0.f);
          O1b[(size_t)gr * 256 + gc] = cvt1(v);
        }
      }
    }
  }
}

// ---- predictor GEMM-2 + fused dot: P[nt][p] = relu(Z1@Wp2+b)[p, nt-half] . wp3 ----
// atomic-free: each (mt, nt) block plain-stores its half-row partial to its plane.
__global__ __launch_bounds__(256) void gemm_dot(
    const unsigned short* __restrict__ Ab,
    const unsigned short* __restrict__ Bh, const float* __restrict__ bias,
    const float* __restrict__ wp3, int M, float* __restrict__ P0, float* __restrict__ P1) {
  __shared__ unsigned short sAh[128 * 40], sBh[128 * 40];
  __shared__ float part[128][33];
  int t = threadIdx.x;
  int mt = blockIdx.x >> 1, nt = blockIdx.x & 1;
  int m0 = mt * 128;
  int n0 = nt * 128;
  int wid = t >> 6, lane = t & 63;
  int wr = (wid >> 1) * 64, wc = (wid & 1) * 64;
  int quad = lane >> 4, lrow = lane & 15;

  f32x4 acc[4][4];
  const f32x4 z4 = {0.f, 0.f, 0.f, 0.f};
#pragma unroll
  for (int i = 0; i < 4; ++i)
#pragma unroll
    for (int j = 0; j < 4; ++j) acc[i][j] = z4;

  int sr = t >> 2;
  int c8 = (t & 3) * 8;

  for (int k0 = 0; k0 < 256; k0 += 32) {
#pragma unroll
    for (int rep = 0; rep < 2; ++rep) {
      int r = sr + rep * 64;
      int arow = m0 + r; if (arow >= M) arow = M - 1;
      *(uint4*)&sAh[r * 40 + c8] = *(const uint4*)&Ab[(size_t)arow * 256 + k0 + c8];
      *(uint4*)&sBh[r * 40 + c8] = *(const uint4*)&Bh[(size_t)(n0 + r) * 256 + k0 + c8];
    }
    __syncthreads();
    bf16x8 ah[4], bh[4];
#pragma unroll
    for (int i = 0; i < 4; ++i) {
      ah[i] = *(const bf16x8*)&sAh[(wr + i * 16 + lrow) * 40 + quad * 8];
      bh[i] = *(const bf16x8*)&sBh[(wc + i * 16 + lrow) * 40 + quad * 8];
    }
#pragma unroll
    for (int i = 0; i < 4; ++i)
#pragma unroll
      for (int j = 0; j < 4; ++j)
        acc[i][j] = __builtin_amdgcn_mfma_f32_16x16x32_bf16(ah[i], bh[j], acc[i][j], 0, 0, 0);
    __syncthreads();
  }

  int cid = (wid & 1) * 16 + lrow;
#pragma unroll
  for (int i = 0; i < 4; ++i) {
#pragma unroll
    for (int rr = 0; rr < 4; ++rr) {
      int rloc = wr + i * 16 + quad * 4 + rr;
      float s = 0.f;
#pragma unroll
      for (int j = 0; j < 4; ++j) {
        int gc = n0 + wc + j * 16 + lrow;
        float v = fmaxf(acc[i][j][rr] + bias[gc], 0.f);
        s += v * wp3[gc];
      }
      part[rloc][cid] = s;
    }
  }
  __syncthreads();
  if (t < 128) {
    int gr = m0 + t;
    if (gr < M) {
      float s = 0.f;
#pragma unroll
      for (int c = 0; c < 32; ++c) s += part[t][c];
      if (nt == 0) P0[gr] = s;
      else         P1[gr] = s;
    }
  }
}

// ---- finish: out[p] = P0[p] + P1[p] + bp3 (dual-dtype store) ----
__global__ void k_finish(const float* __restrict__ P0, const float* __restrict__ P1,
                         const float* __restrict__ bp3, void* __restrict__ out,
                         int n, const int* __restrict__ flagp) {
  int p = blockIdx.x * 256 + threadIdx.x;
  if (p >= n) return;
  float r = P0[p] + P1[p] + bp3[0];
  if (*flagp) ((float*)out)[p] = r;
  else        ((unsigned short*)out)[p] = f2bf(r);
}

extern "C" void kernel_launch(void* const* d_in, const int* in_sizes, int n_in,
                              void* d_out, int out_size, void* d_ws, size_t ws_size,
                              hipStream_t stream) {
  const int N = 50000, E = 800000, P = 100000, DIN = 128, DH = 256;
  const int M2 = 2 * P;                 // 200000 predictor rows
  const void* x = d_in[0];
  const int* esrc = (const int*)d_in[1];
  const int* edst = (const int*)d_in[2];
  const int* psrc = (const int*)d_in[3];
  const int* pdst = (const int*)d_in[4];
  const int* nsrc = (const int*)d_in[5];
  const int* ndst = (const int*)d_in[6];
  const void* Ws0 = d_in[7];  const void* Wn0 = d_in[8];  const void* b0 = d_in[9];
  const void* Ws1 = d_in[10]; const void* Wn1 = d_in[11]; const void* b1 = d_in[12];
  const void* Ws2 = d_in[13]; const void* Wn2 = d_in[14]; const void* b2 = d_in[15];
  const void* Wp1 = d_in[16]; const void* bp1 = d_in[17];
  const void* Wp2 = d_in[18]; const void* bp2 = d_in[19];
  const void* Wp3 = d_in[20]; const void* bp3 = d_in[21];
  (void)in_sizes; (void)n_in; (void)out_size; (void)ws_size;

  // ---- workspace layout ----
  const size_t NH = (size_t)N * DH;               // 12.8M elems
  unsigned short* Hb = (unsigned short*)d_ws;     // [N,256] bf16 (also Xb for L0)
  unsigned short* Xb = Hb;
  char* reg1 = (char*)d_ws + NH * 2;              // 102.4 MB region
  unsigned int* Yp = (unsigned int*)reg1;         // layers: [N,256] packed u32
  unsigned short* Zh = (unsigned short*)(reg1 + NH * 4);  // layers: [N,256] bf16
  unsigned short* Z1b = (unsigned short*)reg1;    // predictor: [200000,256] bf16
  float* P0 = (float*)(reg1 + (size_t)M2 * 256 * 2);      // [200000] fp32 x2
  float* P1 = P0 + M2;
  unsigned short* W16 = (unsigned short*)(P1 + M2);
  unsigned short* ws0h = W16;                     // K=128: 32768 each
  unsigned short* wn0h = ws0h + 32768;
  unsigned short* ws1h = wn0h + 32768;            // K=256: 65536 each
  unsigned short* wn1h = ws1h + 65536;
  unsigned short* ws2h = wn1h + 65536;
  unsigned short* wn2h = ws2h + 65536;
  unsigned short* wp1h = wn2h + 65536;
  unsigned short* wp2h = wp1h + 65536;
  float* FB = (float*)(wp2h + 65536);
  float* b0f  = FB;
  float* b1f  = b0f + 256;
  float* b2f  = b1f + 256;
  float* bp1f = b2f + 256;
  float* bp2f = bp1f + 256;
  float* wp3f = bp2f + 256;
  float* bp3f = wp3f + 256;
  int* deg   = (int*)(bp3f + 4);
  int* offs  = deg + N;
  int* cur   = offs + (N + 1);
  int* bsums = cur + N;
  int* csr   = bsums + 256;
  int* flagp = csr + E;

  // ---- dtype detection ----
  k_detect<<<1, 256, 0, stream>>>((const unsigned short*)x, 8192, flagp);

  // ---- weight transpose-to-bf16 + small cvts ----
  k_wh<<<CDIV(DIN * DH, 256), 256, 0, stream>>>(Ws0, ws0h, DIN, flagp);
  k_wh<<<CDIV(DIN * DH, 256), 256, 0, stream>>>(Wn0, wn0h, DIN, flagp);
  k_wh<<<CDIV(DH * DH, 256), 256, 0, stream>>>(Ws1, ws1h, DH, flagp);
  k_wh<<<CDIV(DH * DH, 256), 256, 0, stream>>>(Wn1, wn1h, DH, flagp);
  k_wh<<<CDIV(DH * DH, 256), 256, 0, stream>>>(Ws2, ws2h, DH, flagp);
  k_wh<<<CDIV(DH * DH, 256), 256, 0, stream>>>(Wn2, wn2h, DH, flagp);
  k_wh<<<CDIV(DH * DH, 256), 256, 0, stream>>>(Wp1, wp1h, DH, flagp);
  k_wh<<<CDIV(DH * DH, 256), 256, 0, stream>>>(Wp2, wp2h, DH, flagp);
  k_cvt7<<<7, 256, 0, stream>>>(b0, b1, b2, bp1, bp2, Wp3, bp3,
                                b0f, b1f, b2f, bp1f, bp2f, wp3f, bp3f, flagp);

  // ---- CSR build (deterministic) ----
  int nb = CDIV(N, 256);
  k_zero_i32<<<nb, 256, 0, stream>>>(deg, N);
  k_deg<<<CDIV(E, 256), 256, 0, stream>>>(edst, deg, E);
  k_scan1<<<nb, 256, 0, stream>>>(deg, offs, bsums, N);
  k_scan2<<<1, 256, 0, stream>>>(bsums, nb);
  k_scan3<<<nb, 256, 0, stream>>>(offs, bsums, N, E);
  k_copy_i32<<<nb, 256, 0, stream>>>(offs, cur, N);
  k_fill<<<CDIV(E, 256), 256, 0, stream>>>(edst, esrc, cur, csr, E);
  k_sortw<<<CDIV(N, 4), 256, 0, stream>>>(offs, csr, N);

  const int MT = CDIV(N, 128);          // 391

  // ---- Layer 0: Y=x@Ws0, Zh=x@Wn0; H = relu(Y + agg(Zh) + b0) ----
  k_xbf16<<<CDIV(N * DIN, 256), 256, 0, stream>>>(x, Xb, N * DIN, flagp);
  gemm2<<<MT * 4, 256, 0, stream>>>(Xb, DIN, ws0h, wn0h, N, Yp, Zh);
  k_aggfuse<<<N / 4, 256, 0, stream>>>(Yp, Zh, offs, csr, b0f, 1, Hb);

  // ---- Layer 1 ----
  gemm2<<<MT * 4, 256, 0, stream>>>(Hb, DH, ws1h, wn1h, N, Yp, Zh);
  k_aggfuse<<<N / 4, 256, 0, stream>>>(Yp, Zh, offs, csr, b1f, 1, Hb);

  // ---- Layer 2 (no relu) ----
  gemm2<<<MT * 4, 256, 0, stream>>>(Hb, DH, ws2h, wn2h, N, Yp, Zh);
  k_aggfuse<<<N / 4, 256, 0, stream>>>(Yp, Zh, offs, csr, b2f, 0, Hb);

  // ---- Predictor, single pass over all 200000 pairs ----
  const int G_P = CDIV(M2, 128) * 2;    // 3126 blocks
  gemm_pred1<<<G_P, 256, 0, stream>>>(Hb, psrc, pdst, nsrc, ndst, P,
                                      wp1h, bp1f, M2, Z1b);
  gemm_dot<<<G_P, 256, 0, stream>>>(Z1b, wp2h, bp2f, wp3f, M2, P0, P1);
  k_finish<<<CDIV(M2, 256), 256, 0, stream>>>(P0, P1, bp3f, d_out, M2, flagp);
}